// Round 9
// baseline (244.725 us; speedup 1.0000x reference)
//
#include <hip/hip_runtime.h>
#include <cstdint>
#include <cstddef>

// ---------------- types / helpers ----------------
typedef _Float16 f16x8 __attribute__((ext_vector_type(8)));
typedef _Float16 f16x4 __attribute__((ext_vector_type(4)));
typedef float    f32x4 __attribute__((ext_vector_type(4)));

#define AS_GLOBAL __attribute__((address_space(1)))
#define AS_LDS    __attribute__((address_space(3)))

__device__ __forceinline__ void load16_to_lds(const _Float16* g, _Float16* l) {
    // async global->LDS, 16 B/lane, LDS dest = wave-uniform base + lane*16
    __builtin_amdgcn_global_load_lds((const AS_GLOBAL void*)g, (AS_LDS void*)l, 16, 0, 0);
}

// ---------------- problem constants ----------------
#define BB   2
#define TT   4096
#define DD   768
#define NH   12
#define HDIM 64
#define D3   2304
// softmax in exp2 domain: scale * log2(e), folded into Q at load
#define SC2  (0.125f * 1.44269504088896f)

// ---------------- prologue: weight transposes only (x-cast fused into gemm_qkv) ----------------
__global__ __launch_bounds__(256) void prep(const float* __restrict__ Wqkv,
                                            _Float16* __restrict__ Wqkvt,
                                            const float* __restrict__ Wout,
                                            _Float16* __restrict__ Wot) {
    const int bid = blockIdx.x, tid = threadIdx.x;
    __shared__ float tile[32][33];
    const float* in; _Float16* out; int C, bx, by;
    if (bid < 1728) {
        const int t = bid;                   // 72 x 24 tiles
        in = Wqkv; out = Wqkvt; C = 2304;
        bx = (t % 72) * 32; by = (t / 72) * 32;
    } else {
        const int t = bid - 1728;            // 24 x 24 tiles
        in = Wout; out = Wot; C = 768;
        bx = (t % 24) * 32; by = (t / 24) * 32;
    }
    const int R = 768;
    const int tx = tid & 31, ty = tid >> 5;  // 32 x 8
#pragma unroll
    for (int j = 0; j < 32; j += 8)
        tile[ty + j][tx] = in[(size_t)(by + ty + j) * C + bx + tx];
    __syncthreads();
#pragma unroll
    for (int j = 0; j < 32; j += 8)
        out[(size_t)(bx + ty + j) * R + by + tx] = (_Float16)tile[tx][ty + j];
}

// ---------------- GEMM body: C[M][N] = A[M][K] * Bt[N][K]^T + bias ----------------
// 128x128 tile, BK=64, 256 threads = 4 waves, each wave 64x64. Exact-fit dims.
// CA/CB: operand is f32 in global (A32/B32); reg-stage with RTE cast to the
// SAME LDS layout global_load_lds produces (lane rowc*8+part -> rowc*64+part*8).
template <typename OutT, bool CA, bool CB>
__device__ __forceinline__ void gemm_body(const _Float16* __restrict__ A,
                                          const float* __restrict__ A32,
                                          const _Float16* __restrict__ Bt,
                                          const float* __restrict__ B32,
                                          const float* __restrict__ bias, bool bias_row,
                                          OutT* __restrict__ C, int N, int K,
                                          int m0, int n0,
                                          _Float16* As, _Float16* Bs) {
    const int tid  = threadIdx.x;
    const int wave = tid >> 6, lane = tid & 63, quad = lane >> 4, l16 = lane & 15;
    const int wm = (wave & 1) * 64, wn = (wave >> 1) * 64;
    const int rowc = lane >> 3, part = lane & 7;   // staging: 8 rows/chunk, 8 lanes/row

    f32x4 acc[4][4];
#pragma unroll
    for (int i = 0; i < 4; ++i)
#pragma unroll
        for (int n = 0; n < 4; ++n) acc[i][n] = f32x4{0.f, 0.f, 0.f, 0.f};

    for (int k0 = 0; k0 < K; k0 += 64) {
        __syncthreads();
#pragma unroll
        for (int cc = 0; cc < 4; ++cc) {
            const int ch = wave * 4 + cc;          // 16 chunks of 8 rows
            if constexpr (CA) {
                const float* src = A32 + (size_t)(m0 + ch * 8 + rowc) * K + k0 + part * 8;
                float4 v0 = *(const float4*)src;
                float4 v1 = *(const float4*)(src + 4);
                f16x8 hv;
                hv[0] = (_Float16)v0.x; hv[1] = (_Float16)v0.y;
                hv[2] = (_Float16)v0.z; hv[3] = (_Float16)v0.w;
                hv[4] = (_Float16)v1.x; hv[5] = (_Float16)v1.y;
                hv[6] = (_Float16)v1.z; hv[7] = (_Float16)v1.w;
                *(f16x8*)(As + ch * 512 + rowc * 64 + part * 8) = hv;
            } else {
                load16_to_lds(A + (size_t)(m0 + ch * 8 + rowc) * K + k0 + part * 8,
                              As + ch * 512);
            }
            if constexpr (CB) {
                const float* src = B32 + (size_t)(n0 + ch * 8 + rowc) * K + k0 + part * 8;
                float4 v0 = *(const float4*)src;
                float4 v1 = *(const float4*)(src + 4);
                f16x8 hv;
                hv[0] = (_Float16)v0.x; hv[1] = (_Float16)v0.y;
                hv[2] = (_Float16)v0.z; hv[3] = (_Float16)v0.w;
                hv[4] = (_Float16)v1.x; hv[5] = (_Float16)v1.y;
                hv[6] = (_Float16)v1.z; hv[7] = (_Float16)v1.w;
                *(f16x8*)(Bs + ch * 512 + rowc * 64 + part * 8) = hv;
            } else {
                load16_to_lds(Bt + (size_t)(n0 + ch * 8 + rowc) * K + k0 + part * 8,
                              Bs + ch * 512);
            }
        }
        __syncthreads();
#pragma unroll
        for (int i = 0; i < 4; ++i) {
            f16x8 a0 = *(const f16x8*)(As + (wm + i * 16 + l16) * 64 + quad * 8);
            f16x8 a1 = *(const f16x8*)(As + (wm + i * 16 + l16) * 64 + 32 + quad * 8);
#pragma unroll
            for (int n = 0; n < 4; ++n) {
                f16x8 b0 = *(const f16x8*)(Bs + (wn + n * 16 + l16) * 64 + quad * 8);
                f16x8 b1 = *(const f16x8*)(Bs + (wn + n * 16 + l16) * 64 + 32 + quad * 8);
                acc[i][n] = __builtin_amdgcn_mfma_f32_16x16x32_f16(a0, b0, acc[i][n], 0, 0, 0);
                acc[i][n] = __builtin_amdgcn_mfma_f32_16x16x32_f16(a1, b1, acc[i][n], 0, 0, 0);
            }
        }
    }
#pragma unroll
    for (int i = 0; i < 4; ++i)
#pragma unroll
        for (int n = 0; n < 4; ++n)
#pragma unroll
            for (int r = 0; r < 4; ++r) {
                const int row = m0 + wm + i * 16 + quad * 4 + r;
                const int col = n0 + wn + n * 16 + l16;
                const float bv = bias_row ? bias[row] : bias[col];
                C[(size_t)row * N + col] = (OutT)(acc[i][n][r] + bv);
            }
}

// merged QK-projection + V^T-projection + fused x-cast (one launch, 1152 blocks)
__global__ __launch_bounds__(256) void gemm_qkv(const float* __restrict__ x,
                                                const _Float16* __restrict__ Wqkvt,
                                                const float* __restrict__ bqkv,
                                                _Float16* __restrict__ QKh,
                                                _Float16* __restrict__ VtG) {
    __shared__ __align__(16) _Float16 As[128 * 64];
    __shared__ __align__(16) _Float16 Bs[128 * 64];
    const int bid = blockIdx.x;
    if (bid < 768) {       // QK: [8192][1536] = cast(x) . Wqkvt[0:1536]^T
        const int bx = bid % 12, by = bid / 12;
        gemm_body<_Float16, true, false>(nullptr, x, Wqkvt, nullptr, bqkv, false,
                                         QKh, 1536, DD, by * 128, bx * 128, As, Bs);
    } else {               // V^T: [768][8192] = Wv^T . cast(x)^T
        const int t = bid - 768;
        const int bx = t % 64, by = t / 64;
        gemm_body<_Float16, false, true>(Wqkvt + (size_t)1536 * DD, nullptr, nullptr, x,
                                         bqkv + 1536, true, VtG,
                                         8192, DD, by * 128, bx * 128, As, Bs);
    }
}

// ---------------- gemm_out: 64x128 tiles, 768 blocks = 3/CU balanced ----------------
// 4 waves as 2(m) x 2(n): each wave 32 x 64. Per-element K-order identical to
// the 128x128 body (same BK=64 loop, same MFMA shape) -> bitwise-same output.
__global__ __launch_bounds__(256) void gemm_out(const _Float16* __restrict__ A,
                                                const _Float16* __restrict__ Bt,
                                                const float* __restrict__ bias,
                                                float* __restrict__ C) {
    __shared__ __align__(16) _Float16 As[64 * 64];    // 8 KB
    __shared__ __align__(16) _Float16 Bs[128 * 64];   // 16 KB
    const int m0 = (int)blockIdx.y * 64, n0 = (int)blockIdx.x * 128;
    const int N = DD, K = DD;
    const int tid  = threadIdx.x;
    const int wave = tid >> 6, lane = tid & 63, quad = lane >> 4, l16 = lane & 15;
    const int wm = (wave & 1) * 32, wn = (wave >> 1) * 64;
    const int rowc = lane >> 3, part = lane & 7;

    f32x4 acc[2][4];
#pragma unroll
    for (int i = 0; i < 2; ++i)
#pragma unroll
        for (int n = 0; n < 4; ++n) acc[i][n] = f32x4{0.f, 0.f, 0.f, 0.f};

    for (int k0 = 0; k0 < K; k0 += 64) {
        __syncthreads();
#pragma unroll
        for (int cc = 0; cc < 2; ++cc) {               // A: 8 chunks of 8 rows
            const int ch = wave * 2 + cc;
            load16_to_lds(A + (size_t)(m0 + ch * 8 + rowc) * K + k0 + part * 8,
                          As + ch * 512);
        }
#pragma unroll
        for (int cc = 0; cc < 4; ++cc) {               // B: 16 chunks of 8 rows
            const int ch = wave * 4 + cc;
            load16_to_lds(Bt + (size_t)(n0 + ch * 8 + rowc) * K + k0 + part * 8,
                          Bs + ch * 512);
        }
        __syncthreads();
#pragma unroll
        for (int i = 0; i < 2; ++i) {
            f16x8 a0 = *(const f16x8*)(As + (wm + i * 16 + l16) * 64 + quad * 8);
            f16x8 a1 = *(const f16x8*)(As + (wm + i * 16 + l16) * 64 + 32 + quad * 8);
#pragma unroll
            for (int n = 0; n < 4; ++n) {
                f16x8 b0 = *(const f16x8*)(Bs + (wn + n * 16 + l16) * 64 + quad * 8);
                f16x8 b1 = *(const f16x8*)(Bs + (wn + n * 16 + l16) * 64 + 32 + quad * 8);
                acc[i][n] = __builtin_amdgcn_mfma_f32_16x16x32_f16(a0, b0, acc[i][n], 0, 0, 0);
                acc[i][n] = __builtin_amdgcn_mfma_f32_16x16x32_f16(a1, b1, acc[i][n], 0, 0, 0);
            }
        }
    }
#pragma unroll
    for (int i = 0; i < 2; ++i)
#pragma unroll
        for (int n = 0; n < 4; ++n)
#pragma unroll
            for (int r = 0; r < 4; ++r) {
                const int row = m0 + wm + i * 16 + quad * 4 + r;
                const int col = n0 + wn + n * 16 + l16;
                C[(size_t)row * N + col] = acc[i][n][r] + bias[col];
            }
}

// ---------------- flash attention: swapped-QK^T, P in registers (R8, frozen) ----------------
// grid 1536 (R3's proven LPT + XCD grouping), 256 threads = 4 waves
// (wq = q-half of 32 rows, wk = k-half of 32 keys), one 64-row q-tile/block.
// Verified R8: 82.9 us, MfmaUtil 47%, VGPR 48, LDS 32 KB (5 blocks/CU).
//
// qk: fp16 [B*T][1536] (Q at h*64, K at 768+h*64)
// vt: fp16 [768][8192]  (V^T: row h*64+d, col b*4096+t)
// ao: fp16 [B*T][768]
__global__ __launch_bounds__(256, 5) void attn_kernel(const _Float16* __restrict__ qk,
                                                      const _Float16* __restrict__ vt,
                                                      _Float16* __restrict__ ao) {
    __shared__ __align__(16) _Float16 Ks[2][64 * 64];
    __shared__ __align__(16) _Float16 Vs[2][64 * 64];

    // ---- decode: R3's exact LPT + XCD grouping (measured-good) ----
    const int L    = blockIdx.x;
    const int xcd  = L & 7;
    const int r_   = L >> 3;          // 0..191
    const int gIdx = r_ % 3;          // group on this XCD
    const int qt   = 63 - r_ / 3;     // heavy tiles dispatch first
    const int g    = gIdx * 8 + xcd;  // head-batch group 0..23
    const int b = g / NH, h = g % NH;

    const int tid = threadIdx.x;
    const int wave = tid >> 6, lane = tid & 63, quad = lane >> 4, l16 = lane & 15;
    const int wq = wave >> 1, wk = wave & 1;   // q-half, k-half

    f16x4 ones4;
#pragma unroll
    for (int j = 0; j < 4; ++j) ones4[j] = (_Float16)1.0f;

    // ---- per-lane 32-bit staging offsets (k0 added as uniform offset) ----
    // K rows: IDENTITY (LDS row j = key k0+j). 16B-chunk XOR swizzle by j&7.
    int vK[2], vV[2];
#pragma unroll
    for (int p = 0; p < 2; ++p) {
        const int j   = wave * 16 + p * 8 + (lane >> 3);
        const int cdk = (lane & 7) ^ (j & 7);           // swizzled source chunk
        vK[p] = (b * TT + j) * 1536 + DD + h * HDIM + cdk * 8;
        vV[p] = (h * HDIM + j) * 8192 + b * TT + cdk * 8;
    }
    auto stage = [&](int buf, int k0) {
        const int kK = k0 * 1536;   // uniform (SGPR) offsets
#pragma unroll
        for (int p = 0; p < 2; ++p) {
            load16_to_lds(qk + (vK[p] + kK), Ks[buf] + (wave * 16 + p * 8) * 64);
            load16_to_lds(vt + (vV[p] + k0), Vs[buf] + (wave * 16 + p * 8) * 64);
        }
    };

    const int q0 = qt * 64;
    const int nkt = qt + 1;
    const int qrow0 = q0 + wq * 32;                 // wave's first q-row
    const int qr_lane = qrow0 + l16;                // lane's q (S^T col); +16 for mq=1
    // Q fragments (B-operand of the swapped QK), pre-scaled by SC2
    f16x8 aq[2][2];
#pragma unroll
    for (int mq = 0; mq < 2; ++mq) {
        const int qoff = (b * TT + qrow0 + mq * 16 + l16) * 1536 + h * HDIM + quad * 8;
        const _Float16 sc = (_Float16)SC2;
        aq[mq][0] = *(const f16x8*)(qk + qoff) * sc;
        aq[mq][1] = *(const f16x8*)(qk + qoff + 32) * sc;
    }
    f32x4 o[2][4], lac[2];
#pragma unroll
    for (int mq = 0; mq < 2; ++mq) {
#pragma unroll
        for (int n = 0; n < 4; ++n) o[mq][n] = f32x4{0.f, 0.f, 0.f, 0.f};
        lac[mq] = f32x4{0.f, 0.f, 0.f, 0.f};
    }

    stage(0, 0);              // prime the pipeline
    int cur = 0;
    for (int kt = 0; kt < nkt; ++kt) {
        __syncthreads();      // drains vmcnt: tile kt published; other buf free
        if (kt + 1 < nkt) stage(cur ^ 1, (kt + 1) * 64);

        __builtin_amdgcn_s_setprio(1);
        // ---- S^T = K Q^T : wave's 32 keys x 32 q-rows, depth 64 ----
        // s[mq][n1]: lane holds S[q = qrow0+mq*16+l16][key = wk*32+n1*16+quad*4+r]
        f32x4 s[2][2];
#pragma unroll
        for (int mq = 0; mq < 2; ++mq)
#pragma unroll
            for (int n1 = 0; n1 < 2; ++n1) s[mq][n1] = f32x4{0.f, 0.f, 0.f, 0.f};
#pragma unroll
        for (int kh = 0; kh < 2; ++kh)
#pragma unroll
            for (int n1 = 0; n1 < 2; ++n1) {
                const int rowK = (wk * 2 + n1) * 16 + l16;          // key row (identity)
                const int pos = (kh * 4 + quad) ^ (l16 & 7);        // d-chunk swizzle
                f16x8 bk = *(const f16x8*)(Ks[cur] + rowK * 64 + pos * 8);
                s[0][n1] = __builtin_amdgcn_mfma_f32_16x16x32_f16(bk, aq[0][kh], s[0][n1], 0, 0, 0);
                s[1][n1] = __builtin_amdgcn_mfma_f32_16x16x32_f16(bk, aq[1][kh], s[1][n1], 0, 0, 0);
            }
        __builtin_amdgcn_s_setprio(0);

        // ---- causal mask (diagonal tile only) ----
        if (kt == nkt - 1) {
#pragma unroll
            for (int mq = 0; mq < 2; ++mq) {
                const int qr = qr_lane + mq * 16;
#pragma unroll
                for (int n1 = 0; n1 < 2; ++n1) {
                    const int kg0 = kt * 64 + wk * 32 + n1 * 16 + quad * 4;
#pragma unroll
                    for (int r = 0; r < 4; ++r)
                        if (kg0 + r > qr) s[mq][n1][r] = -1e30f;
                }
            }
        }

        // ---- P = exp2(S^T) directly into x16 A-fragments (VGPR only) ----
        f16x4 pa[2][2];
#pragma unroll
        for (int mq = 0; mq < 2; ++mq)
#pragma unroll
            for (int n1 = 0; n1 < 2; ++n1)
#pragma unroll
                for (int r = 0; r < 4; ++r)
                    pa[mq][n1][r] = (_Float16)__builtin_amdgcn_exp2f(s[mq][n1][r]);

        __builtin_amdgcn_s_setprio(1);
        // ---- l += P . 1 (x16, all-ones B; C rows = q = quad*4+r) ----
#pragma unroll
        for (int mq = 0; mq < 2; ++mq) {
            lac[mq] = __builtin_amdgcn_mfma_f32_16x16x16f16(pa[mq][0], ones4, lac[mq], 0, 0, 0);
            lac[mq] = __builtin_amdgcn_mfma_f32_16x16x16f16(pa[mq][1], ones4, lac[mq], 0, 0, 0);
        }
        // ---- O += P V (x16; B = V[key=quad*4+r][d=n*16+l16], b64 reads) ----
#pragma unroll
        for (int n1 = 0; n1 < 2; ++n1)
#pragma unroll
            for (int n = 0; n < 4; ++n) {
                const int rowV = n * 16 + l16;                       // d row
                const int lc  = wk * 4 + n1 * 2 + (quad >> 1);       // logical 16B chunk
                const int pc  = lc ^ (l16 & 7);                      // phys (stage swz)
                f16x4 bv = *(const f16x4*)(Vs[cur] + rowV * 64 + pc * 8 + (quad & 1) * 4);
                o[0][n] = __builtin_amdgcn_mfma_f32_16x16x16f16(pa[0][n1], bv, o[0][n], 0, 0, 0);
                o[1][n] = __builtin_amdgcn_mfma_f32_16x16x16f16(pa[1][n1], bv, o[1][n], 0, 0, 0);
            }
        __builtin_amdgcn_s_setprio(0);
        cur ^= 1;
    }

    // ---- k-half combine via LDS (block-local, no fences): wk=1 waves park
    // (o, lac) in dead Ks/Vs; wk=0 waves add, divide, store ----
    __syncthreads();          // all LDS reads of the loop complete
    float* const Ksf = (float*)&Ks[0][0];   // o scratch: 8 KB per wq
    float* const Vsf = (float*)&Vs[0][0];   // lac scratch (first 256 B)
    if (wk) {
#pragma unroll
        for (int mq = 0; mq < 2; ++mq) {
            if (l16 == 0)
                *(f32x4*)(Vsf + wq * 32 + mq * 16 + quad * 4) = lac[mq];
#pragma unroll
            for (int n = 0; n < 4; ++n)
                *(f32x4*)(Ksf + wq * 2048 + (mq * 4 + n) * 256 + lane * 4) = o[mq][n];
        }
    }
    __syncthreads();          // partials visible block-wide
    if (!wk) {
#pragma unroll
        for (int mq = 0; mq < 2; ++mq) {
            f32x4 lp = *(const f32x4*)(Vsf + wq * 32 + mq * 16 + quad * 4);
            f32x4 inv;
#pragma unroll
            for (int r = 0; r < 4; ++r) inv[r] = 1.0f / (lac[mq][r] + lp[r]);
#pragma unroll
            for (int n = 0; n < 4; ++n) {
                f32x4 op = *(const f32x4*)(Ksf + wq * 2048 + (mq * 4 + n) * 256 + lane * 4);
#pragma unroll
                for (int r = 0; r < 4; ++r) {
                    const int ooff = (b * TT + qrow0 + mq * 16 + quad * 4 + r) * DD + h * HDIM + l16;
                    ao[ooff + n * 16] = (_Float16)((o[mq][n][r] + op[r]) * inv[r]);
                }
            }
        }
    }
}

// ---------------- launch ----------------
extern "C" void kernel_launch(void* const* d_in, const int* in_sizes, int n_in,
                              void* d_out, int out_size, void* d_ws, size_t ws_size,
                              hipStream_t stream) {
    const float* x     = (const float*)d_in[0];   // [2,4096,768]
    const float* Wqkv  = (const float*)d_in[1];   // [768,2304]
    const float* bqkv  = (const float*)d_in[2];   // [2304]
    const float* Wout  = (const float*)d_in[3];   // [768,768]
    const float* bout  = (const float*)d_in[4];   // [768]
    float* out = (float*)d_out;                   // [2,4096,768]

    char* ws = (char*)d_ws;
    _Float16* Wqkvt = (_Float16*)ws;  ws += (size_t)D3 * DD * 2;         // 3.5 MB
    _Float16* Wot   = (_Float16*)ws;  ws += (size_t)DD * DD * 2;         // 1.2 MB
    _Float16* QKh   = (_Float16*)ws;  ws += (size_t)BB * TT * 1536 * 2;  // 25.2 MB
    _Float16* VtG   = (_Float16*)ws;  ws += (size_t)DD * BB * TT * 2;    // 12.6 MB
    _Float16* AOh   = (_Float16*)ws;  ws += (size_t)BB * TT * DD * 2;    // 12.6 MB

    prep<<<2304, 256, 0, stream>>>(Wqkv, Wqkvt, Wout, Wot);

    gemm_qkv<<<1152, 256, 0, stream>>>(x, Wqkvt, bqkv, QKh, VtG);

    attn_kernel<<<1536, 256, 0, stream>>>(QKh, VtG, AOh);

    gemm_out<<<dim3(DD / 128, (BB * TT) / 64), 256, 0, stream>>>(AOh, Wot, bout, out);
}

// Round 10
// 238.952 us; speedup vs baseline: 1.0242x; 1.0242x over previous
//
#include <hip/hip_runtime.h>
#include <cstdint>
#include <cstddef>

// ---------------- types / helpers ----------------
typedef _Float16 f16x8 __attribute__((ext_vector_type(8)));
typedef _Float16 f16x4 __attribute__((ext_vector_type(4)));
typedef float    f32x4 __attribute__((ext_vector_type(4)));

#define AS_GLOBAL __attribute__((address_space(1)))
#define AS_LDS    __attribute__((address_space(3)))

__device__ __forceinline__ void load16_to_lds(const _Float16* g, _Float16* l) {
    // async global->LDS, 16 B/lane, LDS dest = wave-uniform base + lane*16
    __builtin_amdgcn_global_load_lds((const AS_GLOBAL void*)g, (AS_LDS void*)l, 16, 0, 0);
}

// ---------------- problem constants ----------------
#define BB   2
#define TT   4096
#define DD   768
#define NH   12
#define HDIM 64
#define D3   2304
// softmax in exp2 domain: scale * log2(e), folded into Q at load
#define SC2  (0.125f * 1.44269504088896f)

// ---------------- merged prologue: cast + both transposes (R8 proven) ----------------
__global__ __launch_bounds__(256) void prep(const float* __restrict__ x,
                                            _Float16* __restrict__ Xh,
                                            const float* __restrict__ Wqkv,
                                            _Float16* __restrict__ Wqkvt,
                                            const float* __restrict__ Wout,
                                            _Float16* __restrict__ Wot) {
    const int bid = blockIdx.x, tid = threadIdx.x;
    if (bid < 6144) {
        const int i = bid * 1024 + tid * 4;
        float4 v = *(const float4*)(x + i);
        f16x4 h;
        h[0] = (_Float16)v.x; h[1] = (_Float16)v.y;
        h[2] = (_Float16)v.z; h[3] = (_Float16)v.w;
        *(f16x4*)(Xh + i) = h;
        return;
    }
    __shared__ float tile[32][33];
    const float* in; _Float16* out; int C, bx, by;
    if (bid < 7872) {
        const int t = bid - 6144;            // 72 x 24 tiles
        in = Wqkv; out = Wqkvt; C = 2304;
        bx = (t % 72) * 32; by = (t / 72) * 32;
    } else {
        const int t = bid - 7872;            // 24 x 24 tiles
        in = Wout; out = Wot; C = 768;
        bx = (t % 24) * 32; by = (t / 24) * 32;
    }
    const int R = 768;
    const int tx = tid & 31, ty = tid >> 5;  // 32 x 8
#pragma unroll
    for (int j = 0; j < 32; j += 8)
        tile[ty + j][tx] = in[(size_t)(by + ty + j) * C + bx + tx];
    __syncthreads();
#pragma unroll
    for (int j = 0; j < 32; j += 8)
        out[(size_t)(bx + ty + j) * R + by + tx] = (_Float16)tile[tx][ty + j];
}

// ---------------- GEMM body: C[M][N] = A[M][K] * Bt[N][K]^T + bias ----------------
// 128x128 tile, BK=64, 256 threads = 4 waves, each wave 64x64. Exact-fit dims.
template <typename OutT>
__device__ __forceinline__ void gemm_body(const _Float16* __restrict__ A,
                                          const _Float16* __restrict__ Bt,
                                          const float* __restrict__ bias, bool bias_row,
                                          OutT* __restrict__ C, int N, int K,
                                          int m0, int n0,
                                          _Float16* As, _Float16* Bs) {
    const int tid  = threadIdx.x;
    const int wave = tid >> 6, lane = tid & 63, quad = lane >> 4, l16 = lane & 15;
    const int wm = (wave & 1) * 64, wn = (wave >> 1) * 64;
    const int rowc = lane >> 3, part = lane & 7;   // staging: 8 rows/chunk, 8 lanes/row

    f32x4 acc[4][4];
#pragma unroll
    for (int i = 0; i < 4; ++i)
#pragma unroll
        for (int n = 0; n < 4; ++n) acc[i][n] = f32x4{0.f, 0.f, 0.f, 0.f};

    for (int k0 = 0; k0 < K; k0 += 64) {
        __syncthreads();
#pragma unroll
        for (int cc = 0; cc < 4; ++cc) {
            const int ch = wave * 4 + cc;          // 16 chunks of 8 rows
            load16_to_lds(A  + (size_t)(m0 + ch * 8 + rowc) * K + k0 + part * 8,
                          As + ch * 512);
            load16_to_lds(Bt + (size_t)(n0 + ch * 8 + rowc) * K + k0 + part * 8,
                          Bs + ch * 512);
        }
        __syncthreads();
#pragma unroll
        for (int i = 0; i < 4; ++i) {
            f16x8 a0 = *(const f16x8*)(As + (wm + i * 16 + l16) * 64 + quad * 8);
            f16x8 a1 = *(const f16x8*)(As + (wm + i * 16 + l16) * 64 + 32 + quad * 8);
#pragma unroll
            for (int n = 0; n < 4; ++n) {
                f16x8 b0 = *(const f16x8*)(Bs + (wn + n * 16 + l16) * 64 + quad * 8);
                f16x8 b1 = *(const f16x8*)(Bs + (wn + n * 16 + l16) * 64 + 32 + quad * 8);
                acc[i][n] = __builtin_amdgcn_mfma_f32_16x16x32_f16(a0, b0, acc[i][n], 0, 0, 0);
                acc[i][n] = __builtin_amdgcn_mfma_f32_16x16x32_f16(a1, b1, acc[i][n], 0, 0, 0);
            }
        }
    }
#pragma unroll
    for (int i = 0; i < 4; ++i)
#pragma unroll
        for (int n = 0; n < 4; ++n)
#pragma unroll
            for (int r = 0; r < 4; ++r) {
                const int row = m0 + wm + i * 16 + quad * 4 + r;
                const int col = n0 + wn + n * 16 + l16;
                const float bv = bias_row ? bias[row] : bias[col];
                C[(size_t)row * N + col] = (OutT)(acc[i][n][r] + bv);
            }
}

// merged QK-projection + V^T-projection, T1 XCD panel-grouping (1152 blocks)
// QK: the 12 blocks sharing one Xh A-panel all land on XCD = panel&7 (was:
// spread over all 8 -> ~98 MB of redundant L3->L2 panel fill; now ~12 MB).
// VT: bx-panels (Xh) grouped so each Xh panel's QK- and VT-readers share the
// SAME XCD L2 (panel&7 in both decodes).
__global__ __launch_bounds__(256) void gemm_qkv(const _Float16* __restrict__ Xh,
                                                const _Float16* __restrict__ Wqkvt,
                                                const float* __restrict__ bqkv,
                                                _Float16* __restrict__ QKh,
                                                _Float16* __restrict__ VtG) {
    __shared__ __align__(16) _Float16 As[128 * 64];
    __shared__ __align__(16) _Float16 Bs[128 * 64];
    const int bid = blockIdx.x;
    if (bid < 768) {       // QK: [8192][1536] = Xh . Wqkvt[0:1536]^T
        const int xcd = bid & 7, j = bid >> 3;     // j in [0,96)
        const int by = xcd + 8 * (j / 12);         // A-panel (Xh rows), 8/XCD
        const int bx = j % 12;
        gemm_body<_Float16>(Xh, Wqkvt, bqkv, false, QKh, 1536, DD,
                            by * 128, bx * 128, As, Bs);
    } else {               // V^T: [768][8192] = Wv^T . Xh^T
        const int t = bid - 768;                   // 768%8==0: xcd = t&7
        const int xcd = t & 7, j = t >> 3;         // j in [0,48)
        const int bx = xcd + 8 * (j / 6);          // B-panel (Xh rows), 8/XCD
        const int by = j % 6;
        gemm_body<_Float16>(Wqkvt + (size_t)1536 * DD, Xh, bqkv + 1536, true, VtG,
                            8192, DD, by * 128, bx * 128, As, Bs);
    }
}

// ---------------- gemm_out: 64x128 tiles, 1D 768 blocks, T1-grouped ----------------
// 3 blocks/CU balanced; the 6 blocks sharing one AOh A-panel land on one XCD
// (panel&7) instead of 6 XCDs (was ~73 MB redundant panel fill, now ~12 MB).
__global__ __launch_bounds__(256) void gemm_out(const _Float16* __restrict__ A,
                                                const _Float16* __restrict__ Bt,
                                                const float* __restrict__ bias,
                                                float* __restrict__ C) {
    __shared__ __align__(16) _Float16 As[64 * 64];    // 8 KB
    __shared__ __align__(16) _Float16 Bs[128 * 64];   // 16 KB
    const int L = blockIdx.x;
    const int xcd = L & 7, j = L >> 3;                // j in [0,96)
    const int by = xcd + 8 * (j / 6);                 // 16 A-panels per XCD
    const int bx = j % 6;
    const int m0 = by * 64, n0 = bx * 128;
    const int N = DD, K = DD;
    const int tid  = threadIdx.x;
    const int wave = tid >> 6, lane = tid & 63, quad = lane >> 4, l16 = lane & 15;
    const int wm = (wave & 1) * 32, wn = (wave >> 1) * 64;
    const int rowc = lane >> 3, part = lane & 7;

    f32x4 acc[2][4];
#pragma unroll
    for (int i = 0; i < 2; ++i)
#pragma unroll
        for (int n = 0; n < 4; ++n) acc[i][n] = f32x4{0.f, 0.f, 0.f, 0.f};

    for (int k0 = 0; k0 < K; k0 += 64) {
        __syncthreads();
#pragma unroll
        for (int cc = 0; cc < 2; ++cc) {               // A: 8 chunks of 8 rows
            const int ch = wave * 2 + cc;
            load16_to_lds(A + (size_t)(m0 + ch * 8 + rowc) * K + k0 + part * 8,
                          As + ch * 512);
        }
#pragma unroll
        for (int cc = 0; cc < 4; ++cc) {               // B: 16 chunks of 8 rows
            const int ch = wave * 4 + cc;
            load16_to_lds(Bt + (size_t)(n0 + ch * 8 + rowc) * K + k0 + part * 8,
                          Bs + ch * 512);
        }
        __syncthreads();
#pragma unroll
        for (int i = 0; i < 2; ++i) {
            f16x8 a0 = *(const f16x8*)(As + (wm + i * 16 + l16) * 64 + quad * 8);
            f16x8 a1 = *(const f16x8*)(As + (wm + i * 16 + l16) * 64 + 32 + quad * 8);
#pragma unroll
            for (int n = 0; n < 4; ++n) {
                f16x8 b0 = *(const f16x8*)(Bs + (wn + n * 16 + l16) * 64 + quad * 8);
                f16x8 b1 = *(const f16x8*)(Bs + (wn + n * 16 + l16) * 64 + 32 + quad * 8);
                acc[i][n] = __builtin_amdgcn_mfma_f32_16x16x32_f16(a0, b0, acc[i][n], 0, 0, 0);
                acc[i][n] = __builtin_amdgcn_mfma_f32_16x16x32_f16(a1, b1, acc[i][n], 0, 0, 0);
            }
        }
    }
#pragma unroll
    for (int i = 0; i < 2; ++i)
#pragma unroll
        for (int n = 0; n < 4; ++n)
#pragma unroll
            for (int r = 0; r < 4; ++r) {
                const int row = m0 + wm + i * 16 + quad * 4 + r;
                const int col = n0 + wn + n * 16 + l16;
                C[(size_t)row * N + col] = acc[i][n][r] + bias[col];
            }
}

// ---------------- flash attention: swapped-QK^T, P in registers (R8, frozen) ----------------
// grid 1536 (R3's proven LPT + XCD grouping), 256 threads = 4 waves
// (wq = q-half of 32 rows, wk = k-half of 32 keys), one 64-row q-tile/block.
// Verified R8: 82.9 us, MfmaUtil 47%, VGPR 48, LDS 32 KB (5 blocks/CU).
//
// qk: fp16 [B*T][1536] (Q at h*64, K at 768+h*64)
// vt: fp16 [768][8192]  (V^T: row h*64+d, col b*4096+t)
// ao: fp16 [B*T][768]
__global__ __launch_bounds__(256, 5) void attn_kernel(const _Float16* __restrict__ qk,
                                                      const _Float16* __restrict__ vt,
                                                      _Float16* __restrict__ ao) {
    __shared__ __align__(16) _Float16 Ks[2][64 * 64];
    __shared__ __align__(16) _Float16 Vs[2][64 * 64];

    // ---- decode: R3's exact LPT + XCD grouping (measured-good) ----
    const int L    = blockIdx.x;
    const int xcd  = L & 7;
    const int r_   = L >> 3;          // 0..191
    const int gIdx = r_ % 3;          // group on this XCD
    const int qt   = 63 - r_ / 3;     // heavy tiles dispatch first
    const int g    = gIdx * 8 + xcd;  // head-batch group 0..23
    const int b = g / NH, h = g % NH;

    const int tid = threadIdx.x;
    const int wave = tid >> 6, lane = tid & 63, quad = lane >> 4, l16 = lane & 15;
    const int wq = wave >> 1, wk = wave & 1;   // q-half, k-half

    f16x4 ones4;
#pragma unroll
    for (int j = 0; j < 4; ++j) ones4[j] = (_Float16)1.0f;

    // ---- per-lane 32-bit staging offsets (k0 added as uniform offset) ----
    // K rows: IDENTITY (LDS row j = key k0+j). 16B-chunk XOR swizzle by j&7.
    int vK[2], vV[2];
#pragma unroll
    for (int p = 0; p < 2; ++p) {
        const int j   = wave * 16 + p * 8 + (lane >> 3);
        const int cdk = (lane & 7) ^ (j & 7);           // swizzled source chunk
        vK[p] = (b * TT + j) * 1536 + DD + h * HDIM + cdk * 8;
        vV[p] = (h * HDIM + j) * 8192 + b * TT + cdk * 8;
    }
    auto stage = [&](int buf, int k0) {
        const int kK = k0 * 1536;   // uniform (SGPR) offsets
#pragma unroll
        for (int p = 0; p < 2; ++p) {
            load16_to_lds(qk + (vK[p] + kK), Ks[buf] + (wave * 16 + p * 8) * 64);
            load16_to_lds(vt + (vV[p] + k0), Vs[buf] + (wave * 16 + p * 8) * 64);
        }
    };

    const int q0 = qt * 64;
    const int nkt = qt + 1;
    const int qrow0 = q0 + wq * 32;                 // wave's first q-row
    const int qr_lane = qrow0 + l16;                // lane's q (S^T col); +16 for mq=1
    // Q fragments (B-operand of the swapped QK), pre-scaled by SC2
    f16x8 aq[2][2];
#pragma unroll
    for (int mq = 0; mq < 2; ++mq) {
        const int qoff = (b * TT + qrow0 + mq * 16 + l16) * 1536 + h * HDIM + quad * 8;
        const _Float16 sc = (_Float16)SC2;
        aq[mq][0] = *(const f16x8*)(qk + qoff) * sc;
        aq[mq][1] = *(const f16x8*)(qk + qoff + 32) * sc;
    }
    f32x4 o[2][4], lac[2];
#pragma unroll
    for (int mq = 0; mq < 2; ++mq) {
#pragma unroll
        for (int n = 0; n < 4; ++n) o[mq][n] = f32x4{0.f, 0.f, 0.f, 0.f};
        lac[mq] = f32x4{0.f, 0.f, 0.f, 0.f};
    }

    stage(0, 0);              // prime the pipeline
    int cur = 0;
    for (int kt = 0; kt < nkt; ++kt) {
        __syncthreads();      // drains vmcnt: tile kt published; other buf free
        if (kt + 1 < nkt) stage(cur ^ 1, (kt + 1) * 64);

        __builtin_amdgcn_s_setprio(1);
        // ---- S^T = K Q^T : wave's 32 keys x 32 q-rows, depth 64 ----
        // s[mq][n1]: lane holds S[q = qrow0+mq*16+l16][key = wk*32+n1*16+quad*4+r]
        f32x4 s[2][2];
#pragma unroll
        for (int mq = 0; mq < 2; ++mq)
#pragma unroll
            for (int n1 = 0; n1 < 2; ++n1) s[mq][n1] = f32x4{0.f, 0.f, 0.f, 0.f};
#pragma unroll
        for (int kh = 0; kh < 2; ++kh)
#pragma unroll
            for (int n1 = 0; n1 < 2; ++n1) {
                const int rowK = (wk * 2 + n1) * 16 + l16;          // key row (identity)
                const int pos = (kh * 4 + quad) ^ (l16 & 7);        // d-chunk swizzle
                f16x8 bk = *(const f16x8*)(Ks[cur] + rowK * 64 + pos * 8);
                s[0][n1] = __builtin_amdgcn_mfma_f32_16x16x32_f16(bk, aq[0][kh], s[0][n1], 0, 0, 0);
                s[1][n1] = __builtin_amdgcn_mfma_f32_16x16x32_f16(bk, aq[1][kh], s[1][n1], 0, 0, 0);
            }
        __builtin_amdgcn_s_setprio(0);

        // ---- causal mask (diagonal tile only) ----
        if (kt == nkt - 1) {
#pragma unroll
            for (int mq = 0; mq < 2; ++mq) {
                const int qr = qr_lane + mq * 16;
#pragma unroll
                for (int n1 = 0; n1 < 2; ++n1) {
                    const int kg0 = kt * 64 + wk * 32 + n1 * 16 + quad * 4;
#pragma unroll
                    for (int r = 0; r < 4; ++r)
                        if (kg0 + r > qr) s[mq][n1][r] = -1e30f;
                }
            }
        }

        // ---- P = exp2(S^T) directly into x16 A-fragments (VGPR only) ----
        f16x4 pa[2][2];
#pragma unroll
        for (int mq = 0; mq < 2; ++mq)
#pragma unroll
            for (int n1 = 0; n1 < 2; ++n1)
#pragma unroll
                for (int r = 0; r < 4; ++r)
                    pa[mq][n1][r] = (_Float16)__builtin_amdgcn_exp2f(s[mq][n1][r]);

        __builtin_amdgcn_s_setprio(1);
        // ---- l += P . 1 (x16, all-ones B; C rows = q = quad*4+r) ----
#pragma unroll
        for (int mq = 0; mq < 2; ++mq) {
            lac[mq] = __builtin_amdgcn_mfma_f32_16x16x16f16(pa[mq][0], ones4, lac[mq], 0, 0, 0);
            lac[mq] = __builtin_amdgcn_mfma_f32_16x16x16f16(pa[mq][1], ones4, lac[mq], 0, 0, 0);
        }
        // ---- O += P V (x16; B = V[key=quad*4+r][d=n*16+l16], b64 reads) ----
#pragma unroll
        for (int n1 = 0; n1 < 2; ++n1)
#pragma unroll
            for (int n = 0; n < 4; ++n) {
                const int rowV = n * 16 + l16;                       // d row
                const int lc  = wk * 4 + n1 * 2 + (quad >> 1);       // logical 16B chunk
                const int pc  = lc ^ (l16 & 7);                      // phys (stage swz)
                f16x4 bv = *(const f16x4*)(Vs[cur] + rowV * 64 + pc * 8 + (quad & 1) * 4);
                o[0][n] = __builtin_amdgcn_mfma_f32_16x16x16f16(pa[0][n1], bv, o[0][n], 0, 0, 0);
                o[1][n] = __builtin_amdgcn_mfma_f32_16x16x16f16(pa[1][n1], bv, o[1][n], 0, 0, 0);
            }
        __builtin_amdgcn_s_setprio(0);
        cur ^= 1;
    }

    // ---- k-half combine via LDS (block-local, no fences): wk=1 waves park
    // (o, lac) in dead Ks/Vs; wk=0 waves add, divide, store ----
    __syncthreads();          // all LDS reads of the loop complete
    float* const Ksf = (float*)&Ks[0][0];   // o scratch: 8 KB per wq
    float* const Vsf = (float*)&Vs[0][0];   // lac scratch (first 256 B)
    if (wk) {
#pragma unroll
        for (int mq = 0; mq < 2; ++mq) {
            if (l16 == 0)
                *(f32x4*)(Vsf + wq * 32 + mq * 16 + quad * 4) = lac[mq];
#pragma unroll
            for (int n = 0; n < 4; ++n)
                *(f32x4*)(Ksf + wq * 2048 + (mq * 4 + n) * 256 + lane * 4) = o[mq][n];
        }
    }
    __syncthreads();          // partials visible block-wide
    if (!wk) {
#pragma unroll
        for (int mq = 0; mq < 2; ++mq) {
            f32x4 lp = *(const f32x4*)(Vsf + wq * 32 + mq * 16 + quad * 4);
            f32x4 inv;
#pragma unroll
            for (int r = 0; r < 4; ++r) inv[r] = 1.0f / (lac[mq][r] + lp[r]);
#pragma unroll
            for (int n = 0; n < 4; ++n) {
                f32x4 op = *(const f32x4*)(Ksf + wq * 2048 + (mq * 4 + n) * 256 + lane * 4);
#pragma unroll
                for (int r = 0; r < 4; ++r) {
                    const int ooff = (b * TT + qrow0 + mq * 16 + quad * 4 + r) * DD + h * HDIM + l16;
                    ao[ooff + n * 16] = (_Float16)((o[mq][n][r] + op[r]) * inv[r]);
                }
            }
        }
    }
}

// ---------------- launch ----------------
extern "C" void kernel_launch(void* const* d_in, const int* in_sizes, int n_in,
                              void* d_out, int out_size, void* d_ws, size_t ws_size,
                              hipStream_t stream) {
    const float* x     = (const float*)d_in[0];   // [2,4096,768]
    const float* Wqkv  = (const float*)d_in[1];   // [768,2304]
    const float* bqkv  = (const float*)d_in[2];   // [2304]
    const float* Wout  = (const float*)d_in[3];   // [768,768]
    const float* bout  = (const float*)d_in[4];   // [768]
    float* out = (float*)d_out;                   // [2,4096,768]

    char* ws = (char*)d_ws;
    _Float16* Xh    = (_Float16*)ws;  ws += (size_t)BB * TT * DD * 2;    // 12.6 MB
    _Float16* Wqkvt = (_Float16*)ws;  ws += (size_t)D3 * DD * 2;         // 3.5 MB
    _Float16* Wot   = (_Float16*)ws;  ws += (size_t)DD * DD * 2;         // 1.2 MB
    _Float16* QKh   = (_Float16*)ws;  ws += (size_t)BB * TT * 1536 * 2;  // 25.2 MB
    _Float16* VtG   = (_Float16*)ws;  ws += (size_t)DD * BB * TT * 2;    // 12.6 MB
    _Float16* AOh   = (_Float16*)ws;  ws += (size_t)BB * TT * DD * 2;    // 12.6 MB

    prep<<<8448, 256, 0, stream>>>(x, Xh, Wqkv, Wqkvt, Wout, Wot);

    gemm_qkv<<<1152, 256, 0, stream>>>(Xh, Wqkvt, bqkv, QKh, VtG);

    attn_kernel<<<1536, 256, 0, stream>>>(QKh, VtG, AOh);

    gemm_out<<<768, 256, 0, stream>>>(AOh, Wot, bout, out);
}

// Round 11
// 234.810 us; speedup vs baseline: 1.0422x; 1.0176x over previous
//
#include <hip/hip_runtime.h>
#include <cstdint>
#include <cstddef>

// ---------------- types / helpers ----------------
typedef _Float16 f16x8 __attribute__((ext_vector_type(8)));
typedef _Float16 f16x4 __attribute__((ext_vector_type(4)));
typedef float    f32x4 __attribute__((ext_vector_type(4)));

#define AS_GLOBAL __attribute__((address_space(1)))
#define AS_LDS    __attribute__((address_space(3)))

__device__ __forceinline__ void load16_to_lds(const _Float16* g, _Float16* l) {
    // async global->LDS, 16 B/lane, LDS dest = wave-uniform base + lane*16
    __builtin_amdgcn_global_load_lds((const AS_GLOBAL void*)g, (AS_LDS void*)l, 16, 0, 0);
}

// ---------------- problem constants ----------------
#define BB   2
#define TT   4096
#define DD   768
#define NH   12
#define HDIM 64
#define D3   2304
// softmax in exp2 domain: scale * log2(e), folded into Q at load
#define SC2  (0.125f * 1.44269504088896f)

// ---------------- merged prologue: cast + both transposes (R8 proven) ----------------
__global__ __launch_bounds__(256) void prep(const float* __restrict__ x,
                                            _Float16* __restrict__ Xh,
                                            const float* __restrict__ Wqkv,
                                            _Float16* __restrict__ Wqkvt,
                                            const float* __restrict__ Wout,
                                            _Float16* __restrict__ Wot) {
    const int bid = blockIdx.x, tid = threadIdx.x;
    if (bid < 6144) {
        const int i = bid * 1024 + tid * 4;
        float4 v = *(const float4*)(x + i);
        f16x4 h;
        h[0] = (_Float16)v.x; h[1] = (_Float16)v.y;
        h[2] = (_Float16)v.z; h[3] = (_Float16)v.w;
        *(f16x4*)(Xh + i) = h;
        return;
    }
    __shared__ float tile[32][33];
    const float* in; _Float16* out; int C, bx, by;
    if (bid < 7872) {
        const int t = bid - 6144;            // 72 x 24 tiles
        in = Wqkv; out = Wqkvt; C = 2304;
        bx = (t % 72) * 32; by = (t / 72) * 32;
    } else {
        const int t = bid - 7872;            // 24 x 24 tiles
        in = Wout; out = Wot; C = 768;
        bx = (t % 24) * 32; by = (t / 24) * 32;
    }
    const int R = 768;
    const int tx = tid & 31, ty = tid >> 5;  // 32 x 8
#pragma unroll
    for (int j = 0; j < 32; j += 8)
        tile[ty + j][tx] = in[(size_t)(by + ty + j) * C + bx + tx];
    __syncthreads();
#pragma unroll
    for (int j = 0; j < 32; j += 8)
        out[(size_t)(bx + ty + j) * R + by + tx] = (_Float16)tile[tx][ty + j];
}

// ---------------- GEMM body: C[M][N] = A[M][K] * Bt[N][K]^T + bias ----------------
// 128x128 tile, BK=64, 256 threads = 4 waves, each wave 64x64. Exact-fit dims.
template <typename OutT>
__device__ __forceinline__ void gemm_body(const _Float16* __restrict__ A,
                                          const _Float16* __restrict__ Bt,
                                          const float* __restrict__ bias, bool bias_row,
                                          OutT* __restrict__ C, int N, int K,
                                          int m0, int n0,
                                          _Float16* As, _Float16* Bs) {
    const int tid  = threadIdx.x;
    const int wave = tid >> 6, lane = tid & 63, quad = lane >> 4, l16 = lane & 15;
    const int wm = (wave & 1) * 64, wn = (wave >> 1) * 64;
    const int rowc = lane >> 3, part = lane & 7;   // staging: 8 rows/chunk, 8 lanes/row

    f32x4 acc[4][4];
#pragma unroll
    for (int i = 0; i < 4; ++i)
#pragma unroll
        for (int n = 0; n < 4; ++n) acc[i][n] = f32x4{0.f, 0.f, 0.f, 0.f};

    for (int k0 = 0; k0 < K; k0 += 64) {
        __syncthreads();
#pragma unroll
        for (int cc = 0; cc < 4; ++cc) {
            const int ch = wave * 4 + cc;          // 16 chunks of 8 rows
            load16_to_lds(A  + (size_t)(m0 + ch * 8 + rowc) * K + k0 + part * 8,
                          As + ch * 512);
            load16_to_lds(Bt + (size_t)(n0 + ch * 8 + rowc) * K + k0 + part * 8,
                          Bs + ch * 512);
        }
        __syncthreads();
#pragma unroll
        for (int i = 0; i < 4; ++i) {
            f16x8 a0 = *(const f16x8*)(As + (wm + i * 16 + l16) * 64 + quad * 8);
            f16x8 a1 = *(const f16x8*)(As + (wm + i * 16 + l16) * 64 + 32 + quad * 8);
#pragma unroll
            for (int n = 0; n < 4; ++n) {
                f16x8 b0 = *(const f16x8*)(Bs + (wn + n * 16 + l16) * 64 + quad * 8);
                f16x8 b1 = *(const f16x8*)(Bs + (wn + n * 16 + l16) * 64 + 32 + quad * 8);
                acc[i][n] = __builtin_amdgcn_mfma_f32_16x16x32_f16(a0, b0, acc[i][n], 0, 0, 0);
                acc[i][n] = __builtin_amdgcn_mfma_f32_16x16x32_f16(a1, b1, acc[i][n], 0, 0, 0);
            }
        }
    }
#pragma unroll
    for (int i = 0; i < 4; ++i)
#pragma unroll
        for (int n = 0; n < 4; ++n)
#pragma unroll
            for (int r = 0; r < 4; ++r) {
                const int row = m0 + wm + i * 16 + quad * 4 + r;
                const int col = n0 + wn + n * 16 + l16;
                const float bv = bias_row ? bias[row] : bias[col];
                C[(size_t)row * N + col] = (OutT)(acc[i][n][r] + bv);
            }
}

// merged QK-projection + V^T-projection, T1 XCD panel-grouping (1152 blocks)
__global__ __launch_bounds__(256) void gemm_qkv(const _Float16* __restrict__ Xh,
                                                const _Float16* __restrict__ Wqkvt,
                                                const float* __restrict__ bqkv,
                                                _Float16* __restrict__ QKh,
                                                _Float16* __restrict__ VtG) {
    __shared__ __align__(16) _Float16 As[128 * 64];
    __shared__ __align__(16) _Float16 Bs[128 * 64];
    const int bid = blockIdx.x;
    if (bid < 768) {       // QK: [8192][1536] = Xh . Wqkvt[0:1536]^T
        const int xcd = bid & 7, j = bid >> 3;     // j in [0,96)
        const int by = xcd + 8 * (j / 12);         // A-panel (Xh rows), 8/XCD
        const int bx = j % 12;
        gemm_body<_Float16>(Xh, Wqkvt, bqkv, false, QKh, 1536, DD,
                            by * 128, bx * 128, As, Bs);
    } else {               // V^T: [768][8192] = Wv^T . Xh^T
        const int t = bid - 768;                   // 768%8==0: xcd = t&7
        const int xcd = t & 7, j = t >> 3;         // j in [0,48)
        const int bx = xcd + 8 * (j / 6);          // B-panel (Xh rows), 8/XCD
        const int by = j % 6;
        gemm_body<_Float16>(Wqkvt + (size_t)1536 * DD, Xh, bqkv + 1536, true, VtG,
                            8192, DD, by * 128, bx * 128, As, Bs);
    }
}

// ---------------- gemm_out: 64x128 tiles, 1D 768 blocks, T1-grouped ----------------
__global__ __launch_bounds__(256) void gemm_out(const _Float16* __restrict__ A,
                                                const _Float16* __restrict__ Bt,
                                                const float* __restrict__ bias,
                                                float* __restrict__ C) {
    __shared__ __align__(16) _Float16 As[64 * 64];    // 8 KB
    __shared__ __align__(16) _Float16 Bs[128 * 64];   // 16 KB
    const int L = blockIdx.x;
    const int xcd = L & 7, j = L >> 3;                // j in [0,96)
    const int by = xcd + 8 * (j / 6);                 // 16 A-panels per XCD
    const int bx = j % 6;
    const int m0 = by * 64, n0 = bx * 128;
    const int N = DD, K = DD;
    const int tid  = threadIdx.x;
    const int wave = tid >> 6, lane = tid & 63, quad = lane >> 4, l16 = lane & 15;
    const int wm = (wave & 1) * 32, wn = (wave >> 1) * 64;
    const int rowc = lane >> 3, part = lane & 7;

    f32x4 acc[2][4];
#pragma unroll
    for (int i = 0; i < 2; ++i)
#pragma unroll
        for (int n = 0; n < 4; ++n) acc[i][n] = f32x4{0.f, 0.f, 0.f, 0.f};

    for (int k0 = 0; k0 < K; k0 += 64) {
        __syncthreads();
#pragma unroll
        for (int cc = 0; cc < 2; ++cc) {               // A: 8 chunks of 8 rows
            const int ch = wave * 2 + cc;
            load16_to_lds(A + (size_t)(m0 + ch * 8 + rowc) * K + k0 + part * 8,
                          As + ch * 512);
        }
#pragma unroll
        for (int cc = 0; cc < 4; ++cc) {               // B: 16 chunks of 8 rows
            const int ch = wave * 4 + cc;
            load16_to_lds(Bt + (size_t)(n0 + ch * 8 + rowc) * K + k0 + part * 8,
                          Bs + ch * 512);
        }
        __syncthreads();
#pragma unroll
        for (int i = 0; i < 2; ++i) {
            f16x8 a0 = *(const f16x8*)(As + (wm + i * 16 + l16) * 64 + quad * 8);
            f16x8 a1 = *(const f16x8*)(As + (wm + i * 16 + l16) * 64 + 32 + quad * 8);
#pragma unroll
            for (int n = 0; n < 4; ++n) {
                f16x8 b0 = *(const f16x8*)(Bs + (wn + n * 16 + l16) * 64 + quad * 8);
                f16x8 b1 = *(const f16x8*)(Bs + (wn + n * 16 + l16) * 64 + 32 + quad * 8);
                acc[i][n] = __builtin_amdgcn_mfma_f32_16x16x32_f16(a0, b0, acc[i][n], 0, 0, 0);
                acc[i][n] = __builtin_amdgcn_mfma_f32_16x16x32_f16(a1, b1, acc[i][n], 0, 0, 0);
            }
        }
    }
#pragma unroll
    for (int i = 0; i < 2; ++i)
#pragma unroll
        for (int n = 0; n < 4; ++n)
#pragma unroll
            for (int r = 0; r < 4; ++r) {
                const int row = m0 + wm + i * 16 + quad * 4 + r;
                const int col = n0 + wn + n * 16 + l16;
                C[(size_t)row * N + col] = acc[i][n][r] + bias[col];
            }
}

// ---------------- flash attention: swapped-QK^T, P in registers ----------------
// R11 changes vs R8 (output bitwise-identical -- accumulation orders preserved):
// (1) V stage/read swizzle rot(j&7)=((j&3)<<1)|(j>>2): each (bank-pair, q1)
//     slot gets exactly 4 lanes (the b64x64 minimum) -> kills the 4-way V
//     conflict (6.39M cycles). K's b128 pattern was already conflict-free.
// (2) n1-split iteration: QK(0) -> exp(0) -> QK(1) -> PV(0) -> exp(1) -> PV(1)
//     lets exp2 (trans pipe) overlap MFMA instead of serializing.
__global__ __launch_bounds__(256, 5) void attn_kernel(const _Float16* __restrict__ qk,
                                                      const _Float16* __restrict__ vt,
                                                      _Float16* __restrict__ ao) {
    __shared__ __align__(16) _Float16 Ks[2][64 * 64];
    __shared__ __align__(16) _Float16 Vs[2][64 * 64];

    // ---- decode: R3's exact LPT + XCD grouping (measured-good) ----
    const int L    = blockIdx.x;
    const int xcd  = L & 7;
    const int r_   = L >> 3;          // 0..191
    const int gIdx = r_ % 3;          // group on this XCD
    const int qt   = 63 - r_ / 3;     // heavy tiles dispatch first
    const int g    = gIdx * 8 + xcd;  // head-batch group 0..23
    const int b = g / NH, h = g % NH;

    const int tid = threadIdx.x;
    const int wave = tid >> 6, lane = tid & 63, quad = lane >> 4, l16 = lane & 15;
    const int wq = wave >> 1, wk = wave & 1;   // q-half, k-half

    f16x4 ones4;
#pragma unroll
    for (int j = 0; j < 4; ++j) ones4[j] = (_Float16)1.0f;

    // ---- per-lane 32-bit staging offsets (k0 added as uniform offset) ----
    // K: 16B-chunk XOR swizzle by (j&7) [b128 reads: perfectly packed].
    // V: XOR by rot(j&7) [b64 reads: uniform 4 lanes per bank-pair slot].
    int vK[2], vV[2];
#pragma unroll
    for (int p = 0; p < 2; ++p) {
        const int j   = wave * 16 + p * 8 + (lane >> 3);
        const int cdk = (lane & 7) ^ (j & 7);
        const int cdv = (lane & 7) ^ (((j & 3) << 1) | ((j >> 2) & 1));
        vK[p] = (b * TT + j) * 1536 + DD + h * HDIM + cdk * 8;
        vV[p] = (h * HDIM + j) * 8192 + b * TT + cdv * 8;
    }
    auto stage = [&](int buf, int k0) {
        const int kK = k0 * 1536;   // uniform (SGPR) offsets
#pragma unroll
        for (int p = 0; p < 2; ++p) {
            load16_to_lds(qk + (vK[p] + kK), Ks[buf] + (wave * 16 + p * 8) * 64);
            load16_to_lds(vt + (vV[p] + k0), Vs[buf] + (wave * 16 + p * 8) * 64);
        }
    };

    const int q0 = qt * 64;
    const int nkt = qt + 1;
    const int qrow0 = q0 + wq * 32;                 // wave's first q-row
    const int qr_lane = qrow0 + l16;                // lane's q (S^T col); +16 for mq=1
    const int rv = ((l16 & 3) << 1) | ((l16 >> 2) & 1);   // rot(rowV&7)
    // Q fragments (B-operand of the swapped QK), pre-scaled by SC2
    f16x8 aq[2][2];
#pragma unroll
    for (int mq = 0; mq < 2; ++mq) {
        const int qoff = (b * TT + qrow0 + mq * 16 + l16) * 1536 + h * HDIM + quad * 8;
        const _Float16 sc = (_Float16)SC2;
        aq[mq][0] = *(const f16x8*)(qk + qoff) * sc;
        aq[mq][1] = *(const f16x8*)(qk + qoff + 32) * sc;
    }
    f32x4 o[2][4], lac[2];
#pragma unroll
    for (int mq = 0; mq < 2; ++mq) {
#pragma unroll
        for (int n = 0; n < 4; ++n) o[mq][n] = f32x4{0.f, 0.f, 0.f, 0.f};
        lac[mq] = f32x4{0.f, 0.f, 0.f, 0.f};
    }

    stage(0, 0);              // prime the pipeline
    int cur = 0;
    for (int kt = 0; kt < nkt; ++kt) {
        __syncthreads();      // drains vmcnt: tile kt published; other buf free
        if (kt + 1 < nkt) stage(cur ^ 1, (kt + 1) * 64);

        f32x4 s[2][2];
        f16x4 pa[2][2];
#pragma unroll
        for (int mq = 0; mq < 2; ++mq)
#pragma unroll
            for (int n1 = 0; n1 < 2; ++n1) s[mq][n1] = f32x4{0.f, 0.f, 0.f, 0.f};

        // ---- per-half helpers (same ops/order as R8, n1-major schedule) ----
        auto qk_half = [&](int n1) {
#pragma unroll
            for (int kh = 0; kh < 2; ++kh) {
                const int rowK = (wk * 2 + n1) * 16 + l16;          // key row (identity)
                const int pos = (kh * 4 + quad) ^ (l16 & 7);        // d-chunk swizzle
                f16x8 bk = *(const f16x8*)(Ks[cur] + rowK * 64 + pos * 8);
                s[0][n1] = __builtin_amdgcn_mfma_f32_16x16x32_f16(bk, aq[0][kh], s[0][n1], 0, 0, 0);
                s[1][n1] = __builtin_amdgcn_mfma_f32_16x16x32_f16(bk, aq[1][kh], s[1][n1], 0, 0, 0);
            }
        };
        auto mask_half = [&](int n1) {
#pragma unroll
            for (int mq = 0; mq < 2; ++mq) {
                const int qr = qr_lane + mq * 16;
                const int kg0 = kt * 64 + wk * 32 + n1 * 16 + quad * 4;
#pragma unroll
                for (int r = 0; r < 4; ++r)
                    if (kg0 + r > qr) s[mq][n1][r] = -1e30f;
            }
        };
        auto exp_half = [&](int n1) {
#pragma unroll
            for (int mq = 0; mq < 2; ++mq)
#pragma unroll
                for (int r = 0; r < 4; ++r)
                    pa[mq][n1][r] = (_Float16)__builtin_amdgcn_exp2f(s[mq][n1][r]);
        };
        auto pv_half = [&](int n1) {
            f16x4 ap0 = pa[0][n1], ap1 = pa[1][n1];
            lac[0] = __builtin_amdgcn_mfma_f32_16x16x16f16(ap0, ones4, lac[0], 0, 0, 0);
            lac[1] = __builtin_amdgcn_mfma_f32_16x16x16f16(ap1, ones4, lac[1], 0, 0, 0);
#pragma unroll
            for (int n = 0; n < 4; ++n) {
                const int rowV = n * 16 + l16;                       // d row
                const int lc  = wk * 4 + n1 * 2 + (quad >> 1);       // logical 16B chunk
                const int pc  = lc ^ rv;                             // phys (rot swz)
                f16x4 bv = *(const f16x4*)(Vs[cur] + rowV * 64 + pc * 8 + (quad & 1) * 4);
                o[0][n] = __builtin_amdgcn_mfma_f32_16x16x16f16(ap0, bv, o[0][n], 0, 0, 0);
                o[1][n] = __builtin_amdgcn_mfma_f32_16x16x16f16(ap1, bv, o[1][n], 0, 0, 0);
            }
        };

        const bool last = (kt == nkt - 1);
        __builtin_amdgcn_s_setprio(1);
        qk_half(0);
        __builtin_amdgcn_s_setprio(0);
        if (last) mask_half(0);
        exp_half(0);
        __builtin_amdgcn_s_setprio(1);
        qk_half(1);           // MFMA overlaps exp(0)'s trans ops
        pv_half(0);           // MFMA overlaps exp(1) below via scheduler
        __builtin_amdgcn_s_setprio(0);
        if (last) mask_half(1);
        exp_half(1);
        __builtin_amdgcn_s_setprio(1);
        pv_half(1);
        __builtin_amdgcn_s_setprio(0);
        cur ^= 1;
    }

    // ---- k-half combine via LDS (block-local, no fences): wk=1 waves park
    // (o, lac) in dead Ks/Vs; wk=0 waves add, divide, store ----
    __syncthreads();          // all LDS reads of the loop complete
    float* const Ksf = (float*)&Ks[0][0];   // o scratch: 8 KB per wq
    float* const Vsf = (float*)&Vs[0][0];   // lac scratch (first 256 B)
    if (wk) {
#pragma unroll
        for (int mq = 0; mq < 2; ++mq) {
            if (l16 == 0)
                *(f32x4*)(Vsf + wq * 32 + mq * 16 + quad * 4) = lac[mq];
#pragma unroll
            for (int n = 0; n < 4; ++n)
                *(f32x4*)(Ksf + wq * 2048 + (mq * 4 + n) * 256 + lane * 4) = o[mq][n];
        }
    }
    __syncthreads();          // partials visible block-wide
    if (!wk) {
#pragma unroll
        for (int mq = 0; mq < 2; ++mq) {
            f32x4 lp = *(const f32x4*)(Vsf + wq * 32 + mq * 16 + quad * 4);
            f32x4 inv;
#pragma unroll
            for (int r = 0; r < 4; ++r) inv[r] = 1.0f / (lac[mq][r] + lp[r]);
#pragma unroll
            for (int n = 0; n < 4; ++n) {
                f32x4 op = *(const f32x4*)(Ksf + wq * 2048 + (mq * 4 + n) * 256 + lane * 4);
#pragma unroll
                for (int r = 0; r < 4; ++r) {
                    const int ooff = (b * TT + qrow0 + mq * 16 + quad * 4 + r) * DD + h * HDIM + l16;
                    ao[ooff + n * 16] = (_Float16)((o[mq][n][r] + op[r]) * inv[r]);
                }
            }
        }
    }
}

// ---------------- launch ----------------
extern "C" void kernel_launch(void* const* d_in, const int* in_sizes, int n_in,
                              void* d_out, int out_size, void* d_ws, size_t ws_size,
                              hipStream_t stream) {
    const float* x     = (const float*)d_in[0];   // [2,4096,768]
    const float* Wqkv  = (const float*)d_in[1];   // [768,2304]
    const float* bqkv  = (const float*)d_in[2];   // [2304]
    const float* Wout  = (const float*)d_in[3];   // [768,768]
    const float* bout  = (const float*)d_in[4];   // [768]
    float* out = (float*)d_out;                   // [2,4096,768]

    char* ws = (char*)d_ws;
    _Float16* Xh    = (_Float16*)ws;  ws += (size_t)BB * TT * DD * 2;    // 12.6 MB
    _Float16* Wqkvt = (_Float16*)ws;  ws += (size_t)D3 * DD * 2;         // 3.5 MB
    _Float16* Wot   = (_Float16*)ws;  ws += (size_t)DD * DD * 2;         // 1.2 MB
    _Float16* QKh   = (_Float16*)ws;  ws += (size_t)BB * TT * 1536 * 2;  // 25.2 MB
    _Float16* VtG   = (_Float16*)ws;  ws += (size_t)DD * BB * TT * 2;    // 12.6 MB
    _Float16* AOh   = (_Float16*)ws;  ws += (size_t)BB * TT * DD * 2;    // 12.6 MB

    prep<<<8448, 256, 0, stream>>>(x, Xh, Wqkv, Wqkvt, Wout, Wot);

    gemm_qkv<<<1152, 256, 0, stream>>>(Xh, Wqkvt, bqkv, QKh, VtG);

    attn_kernel<<<1536, 256, 0, stream>>>(QKh, VtG, AOh);

    gemm_out<<<768, 256, 0, stream>>>(AOh, Wot, bout, out);
}

// Round 12
// 231.481 us; speedup vs baseline: 1.0572x; 1.0144x over previous
//
#include <hip/hip_runtime.h>
#include <cstdint>
#include <cstddef>

// ---------------- types / helpers ----------------
typedef _Float16 f16x8 __attribute__((ext_vector_type(8)));
typedef _Float16 f16x4 __attribute__((ext_vector_type(4)));
typedef float    f32x4 __attribute__((ext_vector_type(4)));

#define AS_GLOBAL __attribute__((address_space(1)))
#define AS_LDS    __attribute__((address_space(3)))

__device__ __forceinline__ void load16_to_lds(const _Float16* g, _Float16* l) {
    // async global->LDS, 16 B/lane, LDS dest = wave-uniform base + lane*16
    __builtin_amdgcn_global_load_lds((const AS_GLOBAL void*)g, (AS_LDS void*)l, 16, 0, 0);
}

// ---------------- problem constants ----------------
#define BB   2
#define TT   4096
#define DD   768
#define NH   12
#define HDIM 64
#define D3   2304
// softmax in exp2 domain: scale * log2(e), folded into Q at load
#define SC2  (0.125f * 1.44269504088896f)

// ---------------- merged prologue: cast + both transposes (R8 proven) ----------------
__global__ __launch_bounds__(256) void prep(const float* __restrict__ x,
                                            _Float16* __restrict__ Xh,
                                            const float* __restrict__ Wqkv,
                                            _Float16* __restrict__ Wqkvt,
                                            const float* __restrict__ Wout,
                                            _Float16* __restrict__ Wot) {
    const int bid = blockIdx.x, tid = threadIdx.x;
    if (bid < 6144) {
        const int i = bid * 1024 + tid * 4;
        float4 v = *(const float4*)(x + i);
        f16x4 h;
        h[0] = (_Float16)v.x; h[1] = (_Float16)v.y;
        h[2] = (_Float16)v.z; h[3] = (_Float16)v.w;
        *(f16x4*)(Xh + i) = h;
        return;
    }
    __shared__ float tile[32][33];
    const float* in; _Float16* out; int C, bx, by;
    if (bid < 7872) {
        const int t = bid - 6144;            // 72 x 24 tiles
        in = Wqkv; out = Wqkvt; C = 2304;
        bx = (t % 72) * 32; by = (t / 72) * 32;
    } else {
        const int t = bid - 7872;            // 24 x 24 tiles
        in = Wout; out = Wot; C = 768;
        bx = (t % 24) * 32; by = (t / 24) * 32;
    }
    const int R = 768;
    const int tx = tid & 31, ty = tid >> 5;  // 32 x 8
#pragma unroll
    for (int j = 0; j < 32; j += 8)
        tile[ty + j][tx] = in[(size_t)(by + ty + j) * C + bx + tx];
    __syncthreads();
#pragma unroll
    for (int j = 0; j < 32; j += 8)
        out[(size_t)(bx + ty + j) * R + by + tx] = (_Float16)tile[tx][ty + j];
}

// ---------------- GEMM body: minimum-2-phase dbuf, BK=32 ----------------
// C[M][N] = A[M][K]*Bt[N][K]^T + bias. 128x128 tile, 256 threads = 4 waves,
// each wave 64x64. K%32==0. LDS: As/Bs each 2 x (128x32) = 16 KB -> 32 KB
// total (same as the old single-buffered BK=64 body -> occupancy preserved).
//
// 2-PHASE (T3 minimum recipe): stage(t+1) is issued right after the barrier,
// BEFORE compute(t) -- the global->LDS latency hides under a full K-step of
// MFMAs instead of being exposed between two barriers (the old 1-phase).
// One barrier per iter (drains vmcnt: buf[cur] published; buf[cur^1] free --
// all waves finished reading it last iter). Per-acc K-chunk order unchanged
// (k, k+32, ... ascending) -> bitwise-identical output to the BK=64 body.
// Bonus: 64 B row stride splits even/odd rows across bank halves -> the
// b128 fragment reads are at the 8-lane/slot minimum (the old 128 B-stride
// layout was 2x-conflicted, cf. m98's 1.7e7 SQ_LDS_BANK_CONFLICT).
template <typename OutT>
__device__ __forceinline__ void gemm_body(const _Float16* __restrict__ A,
                                          const _Float16* __restrict__ Bt,
                                          const float* __restrict__ bias, bool bias_row,
                                          OutT* __restrict__ C, int N, int K,
                                          int m0, int n0,
                                          _Float16* As, _Float16* Bs) {
    const int tid  = threadIdx.x;
    const int wave = tid >> 6, lane = tid & 63, quad = lane >> 4, l16 = lane & 15;
    const int wm = (wave & 1) * 64, wn = (wave >> 1) * 64;

    f32x4 acc[4][4];
#pragma unroll
    for (int i = 0; i < 4; ++i)
#pragma unroll
        for (int n = 0; n < 4; ++n) acc[i][n] = f32x4{0.f, 0.f, 0.f, 0.f};

    // staging: j = p*256 + tid covers 512 slots; row = j>>2 (4 lanes/row of
    // 32 halfs), part = j&3. LDS dest offset = j*8 halfs (linear, = row*32+part*8).
    auto stage = [&](int buf, int k0) {
#pragma unroll
        for (int p = 0; p < 2; ++p) {
            const int j = p * 256 + wave * 64 + lane;
            const int row = j >> 2, part = j & 3;
            load16_to_lds(A  + (size_t)(m0 + row) * K + k0 + part * 8,
                          As + buf * 4096 + (p * 256 + wave * 64) * 8);
            load16_to_lds(Bt + (size_t)(n0 + row) * K + k0 + part * 8,
                          Bs + buf * 4096 + (p * 256 + wave * 64) * 8);
        }
    };

    const int nt = K >> 5;
    stage(0, 0);
    int cur = 0;
    for (int t = 0; t < nt; ++t) {
        __syncthreads();          // drains vmcnt: buf[cur] ready; buf[cur^1] free
        if (t + 1 < nt) stage(cur ^ 1, (t + 1) * 32);
#pragma unroll
        for (int i = 0; i < 4; ++i) {
            f16x8 a = *(const f16x8*)(As + cur * 4096 + (wm + i * 16 + l16) * 32 + quad * 8);
#pragma unroll
            for (int n = 0; n < 4; ++n) {
                f16x8 b = *(const f16x8*)(Bs + cur * 4096 + (wn + n * 16 + l16) * 32 + quad * 8);
                acc[i][n] = __builtin_amdgcn_mfma_f32_16x16x32_f16(a, b, acc[i][n], 0, 0, 0);
            }
        }
        cur ^= 1;
    }
#pragma unroll
    for (int i = 0; i < 4; ++i)
#pragma unroll
        for (int n = 0; n < 4; ++n)
#pragma unroll
            for (int r = 0; r < 4; ++r) {
                const int row = m0 + wm + i * 16 + quad * 4 + r;
                const int col = n0 + wn + n * 16 + l16;
                const float bv = bias_row ? bias[row] : bias[col];
                C[(size_t)row * N + col] = (OutT)(acc[i][n][r] + bv);
            }
}

// merged QK-projection + V^T-projection, T1 XCD panel-grouping (1152 blocks)
__global__ __launch_bounds__(256) void gemm_qkv(const _Float16* __restrict__ Xh,
                                                const _Float16* __restrict__ Wqkvt,
                                                const float* __restrict__ bqkv,
                                                _Float16* __restrict__ QKh,
                                                _Float16* __restrict__ VtG) {
    __shared__ __align__(16) _Float16 As[2 * 128 * 32];
    __shared__ __align__(16) _Float16 Bs[2 * 128 * 32];
    const int bid = blockIdx.x;
    if (bid < 768) {       // QK: [8192][1536] = Xh . Wqkvt[0:1536]^T
        const int xcd = bid & 7, j = bid >> 3;     // j in [0,96)
        const int by = xcd + 8 * (j / 12);         // A-panel (Xh rows), 8/XCD
        const int bx = j % 12;
        gemm_body<_Float16>(Xh, Wqkvt, bqkv, false, QKh, 1536, DD,
                            by * 128, bx * 128, As, Bs);
    } else {               // V^T: [768][8192] = Wv^T . Xh^T
        const int t = bid - 768;                   // 768%8==0: xcd = t&7
        const int xcd = t & 7, j = t >> 3;         // j in [0,48)
        const int bx = xcd + 8 * (j / 6);          // B-panel (Xh rows), 8/XCD
        const int by = j % 6;
        gemm_body<_Float16>(Wqkvt + (size_t)1536 * DD, Xh, bqkv + 1536, true, VtG,
                            8192, DD, by * 128, bx * 128, As, Bs);
    }
}

// ---------------- gemm_out: 64x128 tiles, 2-phase dbuf BK=32, T1-grouped ----------------
// 768 blocks = 3/CU balanced. LDS: As 2x(64x32)=8 KB + Bs 2x(128x32)=16 KB.
__global__ __launch_bounds__(256) void gemm_out(const _Float16* __restrict__ A,
                                                const _Float16* __restrict__ Bt,
                                                const float* __restrict__ bias,
                                                float* __restrict__ C) {
    __shared__ __align__(16) _Float16 As[2 * 64 * 32];
    __shared__ __align__(16) _Float16 Bs[2 * 128 * 32];
    const int L = blockIdx.x;
    const int xcd = L & 7, j = L >> 3;                // j in [0,96)
    const int by = xcd + 8 * (j / 6);                 // 16 A-panels per XCD
    const int bx = j % 6;
    const int m0 = by * 64, n0 = bx * 128;
    const int N = DD, K = DD;
    const int tid  = threadIdx.x;
    const int wave = tid >> 6, lane = tid & 63, quad = lane >> 4, l16 = lane & 15;
    const int wm = (wave & 1) * 32, wn = (wave >> 1) * 64;

    f32x4 acc[2][4];
#pragma unroll
    for (int i = 0; i < 2; ++i)
#pragma unroll
        for (int n = 0; n < 4; ++n) acc[i][n] = f32x4{0.f, 0.f, 0.f, 0.f};

    auto stage = [&](int buf, int k0) {
        {   // A: 64 rows x 32 halfs = 256 slots, one pass
            const int jj = wave * 64 + lane;
            const int row = jj >> 2, part = jj & 3;
            load16_to_lds(A + (size_t)(m0 + row) * K + k0 + part * 8,
                          As + buf * 2048 + (wave * 64) * 8);
        }
#pragma unroll
        for (int p = 0; p < 2; ++p) {   // B: 128 rows, two passes
            const int jj = p * 256 + wave * 64 + lane;
            const int row = jj >> 2, part = jj & 3;
            load16_to_lds(Bt + (size_t)(n0 + row) * K + k0 + part * 8,
                          Bs + buf * 4096 + (p * 256 + wave * 64) * 8);
        }
    };

    const int nt = K >> 5;    // 24
    stage(0, 0);
    int cur = 0;
    for (int t = 0; t < nt; ++t) {
        __syncthreads();
        if (t + 1 < nt) stage(cur ^ 1, (t + 1) * 32);
#pragma unroll
        for (int i = 0; i < 2; ++i) {
            f16x8 a = *(const f16x8*)(As + cur * 2048 + (wm + i * 16 + l16) * 32 + quad * 8);
#pragma unroll
            for (int n = 0; n < 4; ++n) {
                f16x8 b = *(const f16x8*)(Bs + cur * 4096 + (wn + n * 16 + l16) * 32 + quad * 8);
                acc[i][n] = __builtin_amdgcn_mfma_f32_16x16x32_f16(a, b, acc[i][n], 0, 0, 0);
            }
        }
        cur ^= 1;
    }
#pragma unroll
    for (int i = 0; i < 2; ++i)
#pragma unroll
        for (int n = 0; n < 4; ++n)
#pragma unroll
            for (int r = 0; r < 4; ++r) {
                const int row = m0 + wm + i * 16 + quad * 4 + r;
                const int col = n0 + wn + n * 16 + l16;
                C[(size_t)row * N + col] = acc[i][n][r] + bias[col];
            }
}

// ---------------- flash attention: swapped-QK^T, P in registers (R11, frozen) ----------------
// 83 us, MfmaUtil 48 + VALUBusy 47 = ~95% dual-pipe issue saturation.
// The 6.39M SQ_LDS_BANK_CONFLICT is the irreducible b64 service minimum
// (counter bit-identical across different V swizzles).
__global__ __launch_bounds__(256, 5) void attn_kernel(const _Float16* __restrict__ qk,
                                                      const _Float16* __restrict__ vt,
                                                      _Float16* __restrict__ ao) {
    __shared__ __align__(16) _Float16 Ks[2][64 * 64];
    __shared__ __align__(16) _Float16 Vs[2][64 * 64];

    // ---- decode: R3's exact LPT + XCD grouping (measured-good) ----
    const int L    = blockIdx.x;
    const int xcd  = L & 7;
    const int r_   = L >> 3;          // 0..191
    const int gIdx = r_ % 3;          // group on this XCD
    const int qt   = 63 - r_ / 3;     // heavy tiles dispatch first
    const int g    = gIdx * 8 + xcd;  // head-batch group 0..23
    const int b = g / NH, h = g % NH;

    const int tid = threadIdx.x;
    const int wave = tid >> 6, lane = tid & 63, quad = lane >> 4, l16 = lane & 15;
    const int wq = wave >> 1, wk = wave & 1;   // q-half, k-half

    f16x4 ones4;
#pragma unroll
    for (int j = 0; j < 4; ++j) ones4[j] = (_Float16)1.0f;

    int vK[2], vV[2];
#pragma unroll
    for (int p = 0; p < 2; ++p) {
        const int j   = wave * 16 + p * 8 + (lane >> 3);
        const int cdk = (lane & 7) ^ (j & 7);
        const int cdv = (lane & 7) ^ (((j & 3) << 1) | ((j >> 2) & 1));
        vK[p] = (b * TT + j) * 1536 + DD + h * HDIM + cdk * 8;
        vV[p] = (h * HDIM + j) * 8192 + b * TT + cdv * 8;
    }
    auto stage = [&](int buf, int k0) {
        const int kK = k0 * 1536;   // uniform (SGPR) offsets
#pragma unroll
        for (int p = 0; p < 2; ++p) {
            load16_to_lds(qk + (vK[p] + kK), Ks[buf] + (wave * 16 + p * 8) * 64);
            load16_to_lds(vt + (vV[p] + k0), Vs[buf] + (wave * 16 + p * 8) * 64);
        }
    };

    const int q0 = qt * 64;
    const int nkt = qt + 1;
    const int qrow0 = q0 + wq * 32;                 // wave's first q-row
    const int qr_lane = qrow0 + l16;                // lane's q (S^T col); +16 for mq=1
    const int rv = ((l16 & 3) << 1) | ((l16 >> 2) & 1);   // rot(rowV&7)
    f16x8 aq[2][2];
#pragma unroll
    for (int mq = 0; mq < 2; ++mq) {
        const int qoff = (b * TT + qrow0 + mq * 16 + l16) * 1536 + h * HDIM + quad * 8;
        const _Float16 sc = (_Float16)SC2;
        aq[mq][0] = *(const f16x8*)(qk + qoff) * sc;
        aq[mq][1] = *(const f16x8*)(qk + qoff + 32) * sc;
    }
    f32x4 o[2][4], lac[2];
#pragma unroll
    for (int mq = 0; mq < 2; ++mq) {
#pragma unroll
        for (int n = 0; n < 4; ++n) o[mq][n] = f32x4{0.f, 0.f, 0.f, 0.f};
        lac[mq] = f32x4{0.f, 0.f, 0.f, 0.f};
    }

    stage(0, 0);              // prime the pipeline
    int cur = 0;
    for (int kt = 0; kt < nkt; ++kt) {
        __syncthreads();      // drains vmcnt: tile kt published; other buf free
        if (kt + 1 < nkt) stage(cur ^ 1, (kt + 1) * 64);

        f32x4 s[2][2];
        f16x4 pa[2][2];
#pragma unroll
        for (int mq = 0; mq < 2; ++mq)
#pragma unroll
            for (int n1 = 0; n1 < 2; ++n1) s[mq][n1] = f32x4{0.f, 0.f, 0.f, 0.f};

        auto qk_half = [&](int n1) {
#pragma unroll
            for (int kh = 0; kh < 2; ++kh) {
                const int rowK = (wk * 2 + n1) * 16 + l16;          // key row (identity)
                const int pos = (kh * 4 + quad) ^ (l16 & 7);        // d-chunk swizzle
                f16x8 bk = *(const f16x8*)(Ks[cur] + rowK * 64 + pos * 8);
                s[0][n1] = __builtin_amdgcn_mfma_f32_16x16x32_f16(bk, aq[0][kh], s[0][n1], 0, 0, 0);
                s[1][n1] = __builtin_amdgcn_mfma_f32_16x16x32_f16(bk, aq[1][kh], s[1][n1], 0, 0, 0);
            }
        };
        auto mask_half = [&](int n1) {
#pragma unroll
            for (int mq = 0; mq < 2; ++mq) {
                const int qr = qr_lane + mq * 16;
                const int kg0 = kt * 64 + wk * 32 + n1 * 16 + quad * 4;
#pragma unroll
                for (int r = 0; r < 4; ++r)
                    if (kg0 + r > qr) s[mq][n1][r] = -1e30f;
            }
        };
        auto exp_half = [&](int n1) {
#pragma unroll
            for (int mq = 0; mq < 2; ++mq)
#pragma unroll
                for (int r = 0; r < 4; ++r)
                    pa[mq][n1][r] = (_Float16)__builtin_amdgcn_exp2f(s[mq][n1][r]);
        };
        auto pv_half = [&](int n1) {
            f16x4 ap0 = pa[0][n1], ap1 = pa[1][n1];
            lac[0] = __builtin_amdgcn_mfma_f32_16x16x16f16(ap0, ones4, lac[0], 0, 0, 0);
            lac[1] = __builtin_amdgcn_mfma_f32_16x16x16f16(ap1, ones4, lac[1], 0, 0, 0);
#pragma unroll
            for (int n = 0; n < 4; ++n) {
                const int rowV = n * 16 + l16;                       // d row
                const int lc  = wk * 4 + n1 * 2 + (quad >> 1);       // logical 16B chunk
                const int pc  = lc ^ rv;                             // phys (rot swz)
                f16x4 bv = *(const f16x4*)(Vs[cur] + rowV * 64 + pc * 8 + (quad & 1) * 4);
                o[0][n] = __builtin_amdgcn_mfma_f32_16x16x16f16(ap0, bv, o[0][n], 0, 0, 0);
                o[1][n] = __builtin_amdgcn_mfma_f32_16x16x16f16(ap1, bv, o[1][n], 0, 0, 0);
            }
        };

        const bool last = (kt == nkt - 1);
        __builtin_amdgcn_s_setprio(1);
        qk_half(0);
        __builtin_amdgcn_s_setprio(0);
        if (last) mask_half(0);
        exp_half(0);
        __builtin_amdgcn_s_setprio(1);
        qk_half(1);           // MFMA overlaps exp(0)'s trans ops
        pv_half(0);           // MFMA overlaps exp(1) below via scheduler
        __builtin_amdgcn_s_setprio(0);
        if (last) mask_half(1);
        exp_half(1);
        __builtin_amdgcn_s_setprio(1);
        pv_half(1);
        __builtin_amdgcn_s_setprio(0);
        cur ^= 1;
    }

    // ---- k-half combine via LDS (block-local, no fences) ----
    __syncthreads();          // all LDS reads of the loop complete
    float* const Ksf = (float*)&Ks[0][0];   // o scratch: 8 KB per wq
    float* const Vsf = (float*)&Vs[0][0];   // lac scratch (first 256 B)
    if (wk) {
#pragma unroll
        for (int mq = 0; mq < 2; ++mq) {
            if (l16 == 0)
                *(f32x4*)(Vsf + wq * 32 + mq * 16 + quad * 4) = lac[mq];
#pragma unroll
            for (int n = 0; n < 4; ++n)
                *(f32x4*)(Ksf + wq * 2048 + (mq * 4 + n) * 256 + lane * 4) = o[mq][n];
        }
    }
    __syncthreads();          // partials visible block-wide
    if (!wk) {
#pragma unroll
        for (int mq = 0; mq < 2; ++mq) {
            f32x4 lp = *(const f32x4*)(Vsf + wq * 32 + mq * 16 + quad * 4);
            f32x4 inv;
#pragma unroll
            for (int r = 0; r < 4; ++r) inv[r] = 1.0f / (lac[mq][r] + lp[r]);
#pragma unroll
            for (int n = 0; n < 4; ++n) {
                f32x4 op = *(const f32x4*)(Ksf + wq * 2048 + (mq * 4 + n) * 256 + lane * 4);
#pragma unroll
                for (int r = 0; r < 4; ++r) {
                    const int ooff = (b * TT + qrow0 + mq * 16 + quad * 4 + r) * DD + h * HDIM + l16;
                    ao[ooff + n * 16] = (_Float16)((o[mq][n][r] + op[r]) * inv[r]);
                }
            }
        }
    }
}

// ---------------- launch ----------------
extern "C" void kernel_launch(void* const* d_in, const int* in_sizes, int n_in,
                              void* d_out, int out_size, void* d_ws, size_t ws_size,
                              hipStream_t stream) {
    const float* x     = (const float*)d_in[0];   // [2,4096,768]
    const float* Wqkv  = (const float*)d_in[1];   // [768,2304]
    const float* bqkv  = (const float*)d_in[2];   // [2304]
    const float* Wout  = (const float*)d_in[3];   // [768,768]
    const float* bout  = (const float*)d_in[4];   // [768]
    float* out = (float*)d_out;                   // [2,4096,768]

    char* ws = (char*)d_ws;
    _Float16* Xh    = (_Float16*)ws;  ws += (size_t)BB * TT * DD * 2;    // 12.6 MB
    _Float16* Wqkvt = (_Float16*)ws;  ws += (size_t)D3 * DD * 2;         // 3.5 MB
    _Float16* Wot   = (_Float16*)ws;  ws += (size_t)DD * DD * 2;         // 1.2 MB
    _Float16* QKh   = (_Float16*)ws;  ws += (size_t)BB * TT * 1536 * 2;  // 25.2 MB
    _Float16* VtG   = (_Float16*)ws;  ws += (size_t)DD * BB * TT * 2;    // 12.6 MB
    _Float16* AOh   = (_Float16*)ws;  ws += (size_t)BB * TT * DD * 2;    // 12.6 MB

    prep<<<8448, 256, 0, stream>>>(x, Xh, Wqkv, Wqkvt, Wout, Wot);

    gemm_qkv<<<1152, 256, 0, stream>>>(Xh, Wqkvt, bqkv, QKh, VtG);

    attn_kernel<<<1536, 256, 0, stream>>>(QKh, VtG, AOh);

    gemm_out<<<768, 256, 0, stream>>>(AOh, Wot, bout, out);
}

// Round 13
// 221.298 us; speedup vs baseline: 1.1059x; 1.0460x over previous
//
#include <hip/hip_runtime.h>
#include <cstdint>
#include <cstddef>

// ---------------- types / helpers ----------------
typedef _Float16 f16x8 __attribute__((ext_vector_type(8)));
typedef _Float16 f16x4 __attribute__((ext_vector_type(4)));
typedef float    f32x4 __attribute__((ext_vector_type(4)));

#define AS_GLOBAL __attribute__((address_space(1)))
#define AS_LDS    __attribute__((address_space(3)))

__device__ __forceinline__ void load16_to_lds(const _Float16* g, _Float16* l) {
    // async global->LDS, 16 B/lane, LDS dest = wave-uniform base + lane*16
    __builtin_amdgcn_global_load_lds((const AS_GLOBAL void*)g, (AS_LDS void*)l, 16, 0, 0);
}

// ---------------- problem constants ----------------
#define BB   2
#define TT   4096
#define DD   768
#define NH   12
#define HDIM 64
#define D3   2304
// softmax in exp2 domain: scale * log2(e), folded into Q at load
#define SC2  (0.125f * 1.44269504088896f)

// ---------------- merged prologue: cast + both transposes (R8 proven) ----------------
__global__ __launch_bounds__(256) void prep(const float* __restrict__ x,
                                            _Float16* __restrict__ Xh,
                                            const float* __restrict__ Wqkv,
                                            _Float16* __restrict__ Wqkvt,
                                            const float* __restrict__ Wout,
                                            _Float16* __restrict__ Wot) {
    const int bid = blockIdx.x, tid = threadIdx.x;
    if (bid < 6144) {
        const int i = bid * 1024 + tid * 4;
        float4 v = *(const float4*)(x + i);
        f16x4 h;
        h[0] = (_Float16)v.x; h[1] = (_Float16)v.y;
        h[2] = (_Float16)v.z; h[3] = (_Float16)v.w;
        *(f16x4*)(Xh + i) = h;
        return;
    }
    __shared__ float tile[32][33];
    const float* in; _Float16* out; int C, bx, by;
    if (bid < 7872) {
        const int t = bid - 6144;            // 72 x 24 tiles
        in = Wqkv; out = Wqkvt; C = 2304;
        bx = (t % 72) * 32; by = (t / 72) * 32;
    } else {
        const int t = bid - 7872;            // 24 x 24 tiles
        in = Wout; out = Wot; C = 768;
        bx = (t % 24) * 32; by = (t / 24) * 32;
    }
    const int R = 768;
    const int tx = tid & 31, ty = tid >> 5;  // 32 x 8
#pragma unroll
    for (int j = 0; j < 32; j += 8)
        tile[ty + j][tx] = in[(size_t)(by + ty + j) * C + bx + tx];
    __syncthreads();
#pragma unroll
    for (int j = 0; j < 32; j += 8)
        out[(size_t)(bx + ty + j) * R + by + tx] = (_Float16)tile[tx][ty + j];
}

// ---------------- GEMM body: 2-phase dbuf, BK=32, parametric tile ----------------
// C[M][N] = A[M][K]*Bt[N][K]^T + bias. Tile = (2*IM*16) x (2*IN*16), 256
// threads = 4 waves as 2x2, each wave (IM*16)x(IN*16). K%32==0.
// 2-PHASE (verified R12): stage(t+1) issued after the barrier, BEFORE
// compute(t) -- global->LDS latency hides under a K-step of MFMAs. One
// barrier/iter. Per-acc K-chunk order (k, k+32, ... ascending, same MFMA
// shape) is tile-shape-independent -> bitwise-identical outputs across
// IM/IN choices.
template <typename OutT, int IM, int IN>
__device__ __forceinline__ void gemm_body(const _Float16* __restrict__ A,
                                          const _Float16* __restrict__ Bt,
                                          const float* __restrict__ bias, bool bias_row,
                                          OutT* __restrict__ C, int N, int K,
                                          int m0, int n0,
                                          _Float16* As, _Float16* Bs) {
    const int tid  = threadIdx.x;
    const int wave = tid >> 6, lane = tid & 63, quad = lane >> 4, l16 = lane & 15;
    const int wm = (wave & 1) * (IM * 16), wn = (wave >> 1) * (IN * 16);
    constexpr int RA = 2 * IM * 16;       // A rows per tile
    constexpr int RB = 2 * IN * 16;       // B rows per tile
    constexpr int PA = RA / 64;           // staging passes (64 rows / pass)
    constexpr int PB = RB / 64;

    f32x4 acc[IM][IN];
#pragma unroll
    for (int i = 0; i < IM; ++i)
#pragma unroll
        for (int n = 0; n < IN; ++n) acc[i][n] = f32x4{0.f, 0.f, 0.f, 0.f};

    // staging: j = p*256 + tid; row = j>>2 (4 lanes x 16B = one 32-half row),
    // part = j&3. LDS dest = linear j*8 halfs (wave-uniform base + lane*16).
    auto stage = [&](int buf, int k0) {
#pragma unroll
        for (int p = 0; p < PA; ++p) {
            const int j = p * 256 + wave * 64 + lane;
            const int row = j >> 2, part = j & 3;
            load16_to_lds(A + (size_t)(m0 + row) * K + k0 + part * 8,
                          As + buf * (RA * 32) + (p * 256 + wave * 64) * 8);
        }
#pragma unroll
        for (int p = 0; p < PB; ++p) {
            const int j = p * 256 + wave * 64 + lane;
            const int row = j >> 2, part = j & 3;
            load16_to_lds(Bt + (size_t)(n0 + row) * K + k0 + part * 8,
                          Bs + buf * (RB * 32) + (p * 256 + wave * 64) * 8);
        }
    };

    const int nt = K >> 5;
    stage(0, 0);
    int cur = 0;
    for (int t = 0; t < nt; ++t) {
        __syncthreads();          // drains vmcnt: buf[cur] ready; buf[cur^1] free
        if (t + 1 < nt) stage(cur ^ 1, (t + 1) * 32);
#pragma unroll
        for (int i = 0; i < IM; ++i) {
            f16x8 a = *(const f16x8*)(As + cur * (RA * 32) + (wm + i * 16 + l16) * 32 + quad * 8);
#pragma unroll
            for (int n = 0; n < IN; ++n) {
                f16x8 b = *(const f16x8*)(Bs + cur * (RB * 32) + (wn + n * 16 + l16) * 32 + quad * 8);
                acc[i][n] = __builtin_amdgcn_mfma_f32_16x16x32_f16(a, b, acc[i][n], 0, 0, 0);
            }
        }
        cur ^= 1;
    }
#pragma unroll
    for (int i = 0; i < IM; ++i)
#pragma unroll
        for (int n = 0; n < IN; ++n)
#pragma unroll
            for (int r = 0; r < 4; ++r) {
                const int row = m0 + wm + i * 16 + quad * 4 + r;
                const int col = n0 + wn + n * 16 + l16;
                const float bv = bias_row ? bias[row] : bias[col];
                C[(size_t)row * N + col] = (OutT)(acc[i][n][r] + bv);
            }
}

// merged QK-projection + V^T-projection: 768 uniform blocks = EXACTLY 3/CU
// (LDS 48 KB forces <=3; perfect balance under any assignment -- R4 lesson).
// QK: 128x192 tiles (512 blocks, IM=4/IN=6); VT: 192x128 (256 blocks,
// IM=6/IN=4). 96 MFMA per 20 KB staged (+20% density vs 128^2's 64/16KB);
// total staged bytes 451->377 MB. T1: Xh panel p's QK-readers AND
// VT-readers both land on XCD p&7 (panel lives in exactly one L2).
__global__ __launch_bounds__(256, 3) void gemm_qkv(const _Float16* __restrict__ Xh,
                                                   const _Float16* __restrict__ Wqkvt,
                                                   const float* __restrict__ bqkv,
                                                   _Float16* __restrict__ QKh,
                                                   _Float16* __restrict__ VtG) {
    __shared__ __align__(16) _Float16 As[2 * 192 * 32];   // 24 KB (max of both)
    __shared__ __align__(16) _Float16 Bs[2 * 192 * 32];   // 24 KB
    const int bid = blockIdx.x;
    if (bid < 512) {       // QK: [8192][1536] = Xh . Wqkvt[0:1536]^T
        const int xcd = bid & 7, j = bid >> 3;     // j in [0,64)
        const int by = xcd + 8 * (j >> 3);         // A-panel (Xh rows), 8/XCD
        const int bx = j & 7;                      // 8 cols of 192
        gemm_body<_Float16, 4, 6>(Xh, Wqkvt, bqkv, false, QKh, 1536, DD,
                                  by * 128, bx * 192, As, Bs);
    } else {               // V^T: [768][8192] = Wv^T . Xh^T
        const int t = bid - 512;                   // t in [0,256)
        const int xcd = t & 7, j = t >> 3;         // j in [0,32)
        const int bn = xcd + 8 * (j >> 2);         // B-panel (Xh rows), 8/XCD
        const int bm = j & 3;                      // 4 rows of 192
        gemm_body<_Float16, 6, 4>(Wqkvt + (size_t)1536 * DD, Xh, bqkv + 1536, true, VtG,
                                  8192, DD, bm * 192, bn * 128, As, Bs);
    }
}

// ---------------- gemm_out: 64x128 tiles via the same template (bitwise same) ----------------
__global__ __launch_bounds__(256) void gemm_out(const _Float16* __restrict__ A,
                                                const _Float16* __restrict__ Bt,
                                                const float* __restrict__ bias,
                                                float* __restrict__ C) {
    __shared__ __align__(16) _Float16 As[2 * 64 * 32];    // 8 KB
    __shared__ __align__(16) _Float16 Bs[2 * 128 * 32];   // 16 KB
    const int L = blockIdx.x;
    const int xcd = L & 7, j = L >> 3;                // j in [0,96)
    const int by = xcd + 8 * (j / 6);                 // 16 A-panels per XCD
    const int bx = j % 6;
    gemm_body<float, 2, 4>(A, Bt, bias, false, C, DD, DD,
                           by * 64, bx * 128, As, Bs);
}

// ---------------- flash attention: swapped-QK^T, P in registers (frozen) ----------------
// 82.5 us, MfmaUtil 48 + VALUBusy 47 = ~95% dual-pipe issue saturation.
// The 6.39M SQ_LDS_BANK_CONFLICT is the irreducible b64 service minimum
// (counter bit-identical across different V swizzles).
__global__ __launch_bounds__(256, 5) void attn_kernel(const _Float16* __restrict__ qk,
                                                      const _Float16* __restrict__ vt,
                                                      _Float16* __restrict__ ao) {
    __shared__ __align__(16) _Float16 Ks[2][64 * 64];
    __shared__ __align__(16) _Float16 Vs[2][64 * 64];

    // ---- decode: R3's exact LPT + XCD grouping (measured-good) ----
    const int L    = blockIdx.x;
    const int xcd  = L & 7;
    const int r_   = L >> 3;          // 0..191
    const int gIdx = r_ % 3;          // group on this XCD
    const int qt   = 63 - r_ / 3;     // heavy tiles dispatch first
    const int g    = gIdx * 8 + xcd;  // head-batch group 0..23
    const int b = g / NH, h = g % NH;

    const int tid = threadIdx.x;
    const int wave = tid >> 6, lane = tid & 63, quad = lane >> 4, l16 = lane & 15;
    const int wq = wave >> 1, wk = wave & 1;   // q-half, k-half

    f16x4 ones4;
#pragma unroll
    for (int j = 0; j < 4; ++j) ones4[j] = (_Float16)1.0f;

    int vK[2], vV[2];
#pragma unroll
    for (int p = 0; p < 2; ++p) {
        const int j   = wave * 16 + p * 8 + (lane >> 3);
        const int cdk = (lane & 7) ^ (j & 7);
        const int cdv = (lane & 7) ^ (((j & 3) << 1) | ((j >> 2) & 1));
        vK[p] = (b * TT + j) * 1536 + DD + h * HDIM + cdk * 8;
        vV[p] = (h * HDIM + j) * 8192 + b * TT + cdv * 8;
    }
    auto stage = [&](int buf, int k0) {
        const int kK = k0 * 1536;   // uniform (SGPR) offsets
#pragma unroll
        for (int p = 0; p < 2; ++p) {
            load16_to_lds(qk + (vK[p] + kK), Ks[buf] + (wave * 16 + p * 8) * 64);
            load16_to_lds(vt + (vV[p] + k0), Vs[buf] + (wave * 16 + p * 8) * 64);
        }
    };

    const int q0 = qt * 64;
    const int nkt = qt + 1;
    const int qrow0 = q0 + wq * 32;                 // wave's first q-row
    const int qr_lane = qrow0 + l16;                // lane's q (S^T col); +16 for mq=1
    const int rv = ((l16 & 3) << 1) | ((l16 >> 2) & 1);   // rot(rowV&7)
    f16x8 aq[2][2];
#pragma unroll
    for (int mq = 0; mq < 2; ++mq) {
        const int qoff = (b * TT + qrow0 + mq * 16 + l16) * 1536 + h * HDIM + quad * 8;
        const _Float16 sc = (_Float16)SC2;
        aq[mq][0] = *(const f16x8*)(qk + qoff) * sc;
        aq[mq][1] = *(const f16x8*)(qk + qoff + 32) * sc;
    }
    f32x4 o[2][4], lac[2];
#pragma unroll
    for (int mq = 0; mq < 2; ++mq) {
#pragma unroll
        for (int n = 0; n < 4; ++n) o[mq][n] = f32x4{0.f, 0.f, 0.f, 0.f};
        lac[mq] = f32x4{0.f, 0.f, 0.f, 0.f};
    }

    stage(0, 0);              // prime the pipeline
    int cur = 0;
    for (int kt = 0; kt < nkt; ++kt) {
        __syncthreads();      // drains vmcnt: tile kt published; other buf free
        if (kt + 1 < nkt) stage(cur ^ 1, (kt + 1) * 64);

        f32x4 s[2][2];
        f16x4 pa[2][2];
#pragma unroll
        for (int mq = 0; mq < 2; ++mq)
#pragma unroll
            for (int n1 = 0; n1 < 2; ++n1) s[mq][n1] = f32x4{0.f, 0.f, 0.f, 0.f};

        auto qk_half = [&](int n1) {
#pragma unroll
            for (int kh = 0; kh < 2; ++kh) {
                const int rowK = (wk * 2 + n1) * 16 + l16;          // key row (identity)
                const int pos = (kh * 4 + quad) ^ (l16 & 7);        // d-chunk swizzle
                f16x8 bk = *(const f16x8*)(Ks[cur] + rowK * 64 + pos * 8);
                s[0][n1] = __builtin_amdgcn_mfma_f32_16x16x32_f16(bk, aq[0][kh], s[0][n1], 0, 0, 0);
                s[1][n1] = __builtin_amdgcn_mfma_f32_16x16x32_f16(bk, aq[1][kh], s[1][n1], 0, 0, 0);
            }
        };
        auto mask_half = [&](int n1) {
#pragma unroll
            for (int mq = 0; mq < 2; ++mq) {
                const int qr = qr_lane + mq * 16;
                const int kg0 = kt * 64 + wk * 32 + n1 * 16 + quad * 4;
#pragma unroll
                for (int r = 0; r < 4; ++r)
                    if (kg0 + r > qr) s[mq][n1][r] = -1e30f;
            }
        };
        auto exp_half = [&](int n1) {
#pragma unroll
            for (int mq = 0; mq < 2; ++mq)
#pragma unroll
                for (int r = 0; r < 4; ++r)
                    pa[mq][n1][r] = (_Float16)__builtin_amdgcn_exp2f(s[mq][n1][r]);
        };
        auto pv_half = [&](int n1) {
            f16x4 ap0 = pa[0][n1], ap1 = pa[1][n1];
            lac[0] = __builtin_amdgcn_mfma_f32_16x16x16f16(ap0, ones4, lac[0], 0, 0, 0);
            lac[1] = __builtin_amdgcn_mfma_f32_16x16x16f16(ap1, ones4, lac[1], 0, 0, 0);
#pragma unroll
            for (int n = 0; n < 4; ++n) {
                const int rowV = n * 16 + l16;                       // d row
                const int lc  = wk * 4 + n1 * 2 + (quad >> 1);       // logical 16B chunk
                const int pc  = lc ^ rv;                             // phys (rot swz)
                f16x4 bv = *(const f16x4*)(Vs[cur] + rowV * 64 + pc * 8 + (quad & 1) * 4);
                o[0][n] = __builtin_amdgcn_mfma_f32_16x16x16f16(ap0, bv, o[0][n], 0, 0, 0);
                o[1][n] = __builtin_amdgcn_mfma_f32_16x16x16f16(ap1, bv, o[1][n], 0, 0, 0);
            }
        };

        const bool last = (kt == nkt - 1);
        __builtin_amdgcn_s_setprio(1);
        qk_half(0);
        __builtin_amdgcn_s_setprio(0);
        if (last) mask_half(0);
        exp_half(0);
        __builtin_amdgcn_s_setprio(1);
        qk_half(1);           // MFMA overlaps exp(0)'s trans ops
        pv_half(0);           // MFMA overlaps exp(1) below via scheduler
        __builtin_amdgcn_s_setprio(0);
        if (last) mask_half(1);
        exp_half(1);
        __builtin_amdgcn_s_setprio(1);
        pv_half(1);
        __builtin_amdgcn_s_setprio(0);
        cur ^= 1;
    }

    // ---- k-half combine via LDS (block-local, no fences) ----
    __syncthreads();          // all LDS reads of the loop complete
    float* const Ksf = (float*)&Ks[0][0];   // o scratch: 8 KB per wq
    float* const Vsf = (float*)&Vs[0][0];   // lac scratch (first 256 B)
    if (wk) {
#pragma unroll
        for (int mq = 0; mq < 2; ++mq) {
            if (l16 == 0)
                *(f32x4*)(Vsf + wq * 32 + mq * 16 + quad * 4) = lac[mq];
#pragma unroll
            for (int n = 0; n < 4; ++n)
                *(f32x4*)(Ksf + wq * 2048 + (mq * 4 + n) * 256 + lane * 4) = o[mq][n];
        }
    }
    __syncthreads();          // partials visible block-wide
    if (!wk) {
#pragma unroll
        for (int mq = 0; mq < 2; ++mq) {
            f32x4 lp = *(const f32x4*)(Vsf + wq * 32 + mq * 16 + quad * 4);
            f32x4 inv;
#pragma unroll
            for (int r = 0; r < 4; ++r) inv[r] = 1.0f / (lac[mq][r] + lp[r]);
#pragma unroll
            for (int n = 0; n < 4; ++n) {
                f32x4 op = *(const f32x4*)(Ksf + wq * 2048 + (mq * 4 + n) * 256 + lane * 4);
#pragma unroll
                for (int r = 0; r < 4; ++r) {
                    const int ooff = (b * TT + qrow0 + mq * 16 + quad * 4 + r) * DD + h * HDIM + l16;
                    ao[ooff + n * 16] = (_Float16)((o[mq][n][r] + op[r]) * inv[r]);
                }
            }
        }
    }
}

// ---------------- launch ----------------
extern "C" void kernel_launch(void* const* d_in, const int* in_sizes, int n_in,
                              void* d_out, int out_size, void* d_ws, size_t ws_size,
                              hipStream_t stream) {
    const float* x     = (const float*)d_in[0];   // [2,4096,768]
    const float* Wqkv  = (const float*)d_in[1];   // [768,2304]
    const float* bqkv  = (const float*)d_in[2];   // [2304]
    const float* Wout  = (const float*)d_in[3];   // [768,768]
    const float* bout  = (const float*)d_in[4];   // [768]
    float* out = (float*)d_out;                   // [2,4096,768]

    char* ws = (char*)d_ws;
    _Float16* Xh    = (_Float16*)ws;  ws += (size_t)BB * TT * DD * 2;    // 12.6 MB
    _Float16* Wqkvt = (_Float16*)ws;  ws += (size_t)D3 * DD * 2;         // 3.5 MB
    _Float16* Wot   = (_Float16*)ws;  ws += (size_t)DD * DD * 2;         // 1.2 MB
    _Float16* QKh   = (_Float16*)ws;  ws += (size_t)BB * TT * 1536 * 2;  // 25.2 MB
    _Float16* VtG   = (_Float16*)ws;  ws += (size_t)DD * BB * TT * 2;    // 12.6 MB
    _Float16* AOh   = (_Float16*)ws;  ws += (size_t)BB * TT * DD * 2;    // 12.6 MB

    prep<<<8448, 256, 0, stream>>>(x, Xh, Wqkv, Wqkvt, Wout, Wot);

    gemm_qkv<<<768, 256, 0, stream>>>(Xh, Wqkvt, bqkv, QKh, VtG);

    attn_kernel<<<1536, 256, 0, stream>>>(QKh, VtG, AOh);

    gemm_out<<<768, 256, 0, stream>>>(AOh, Wot, bout, out);
}

// Round 14
// 214.044 us; speedup vs baseline: 1.1433x; 1.0339x over previous
//
#include <hip/hip_runtime.h>
#include <cstdint>
#include <cstddef>

// ---------------- types / helpers ----------------
typedef _Float16 f16x8 __attribute__((ext_vector_type(8)));
typedef _Float16 f16x4 __attribute__((ext_vector_type(4)));
typedef float    f32x4 __attribute__((ext_vector_type(4)));

#define AS_GLOBAL __attribute__((address_space(1)))
#define AS_LDS    __attribute__((address_space(3)))

__device__ __forceinline__ void load16_to_lds(const _Float16* g, _Float16* l) {
    // async global->LDS, 16 B/lane, LDS dest = wave-uniform base + lane*16
    __builtin_amdgcn_global_load_lds((const AS_GLOBAL void*)g, (AS_LDS void*)l, 16, 0, 0);
}

// ---------------- problem constants ----------------
#define BB   2
#define TT   4096
#define DD   768
#define NH   12
#define HDIM 64
#define D3   2304
// softmax in exp2 domain: scale * log2(e), folded into Q at load
#define SC2  (0.125f * 1.44269504088896f)

// ---------------- merged prologue: cast + both transposes (R8 proven) ----------------
__global__ __launch_bounds__(256) void prep(const float* __restrict__ x,
                                            _Float16* __restrict__ Xh,
                                            const float* __restrict__ Wqkv,
                                            _Float16* __restrict__ Wqkvt,
                                            const float* __restrict__ Wout,
                                            _Float16* __restrict__ Wot) {
    const int bid = blockIdx.x, tid = threadIdx.x;
    if (bid < 6144) {
        const int i = bid * 1024 + tid * 4;
        float4 v = *(const float4*)(x + i);
        f16x4 h;
        h[0] = (_Float16)v.x; h[1] = (_Float16)v.y;
        h[2] = (_Float16)v.z; h[3] = (_Float16)v.w;
        *(f16x4*)(Xh + i) = h;
        return;
    }
    __shared__ float tile[32][33];
    const float* in; _Float16* out; int C, bx, by;
    if (bid < 7872) {
        const int t = bid - 6144;            // 72 x 24 tiles
        in = Wqkv; out = Wqkvt; C = 2304;
        bx = (t % 72) * 32; by = (t / 72) * 32;
    } else {
        const int t = bid - 7872;            // 24 x 24 tiles
        in = Wout; out = Wot; C = 768;
        bx = (t % 24) * 32; by = (t / 24) * 32;
    }
    const int R = 768;
    const int tx = tid & 31, ty = tid >> 5;  // 32 x 8
#pragma unroll
    for (int j = 0; j < 32; j += 8)
        tile[ty + j][tx] = in[(size_t)(by + ty + j) * C + bx + tx];
    __syncthreads();
#pragma unroll
    for (int j = 0; j < 32; j += 8)
        out[(size_t)(bx + ty + j) * R + by + tx] = (_Float16)tile[tx][ty + j];
}

// ---------------- GEMM body: 2-phase dbuf, BK=32, parametric tile (R13) ----------------
template <typename OutT, int IM, int IN>
__device__ __forceinline__ void gemm_body(const _Float16* __restrict__ A,
                                          const _Float16* __restrict__ Bt,
                                          const float* __restrict__ bias, bool bias_row,
                                          OutT* __restrict__ C, int N, int K,
                                          int m0, int n0,
                                          _Float16* As, _Float16* Bs) {
    const int tid  = threadIdx.x;
    const int wave = tid >> 6, lane = tid & 63, quad = lane >> 4, l16 = lane & 15;
    const int wm = (wave & 1) * (IM * 16), wn = (wave >> 1) * (IN * 16);
    constexpr int RA = 2 * IM * 16;       // A rows per tile
    constexpr int RB = 2 * IN * 16;       // B rows per tile
    constexpr int PA = RA / 64;           // staging passes (64 rows / pass)
    constexpr int PB = RB / 64;

    f32x4 acc[IM][IN];
#pragma unroll
    for (int i = 0; i < IM; ++i)
#pragma unroll
        for (int n = 0; n < IN; ++n) acc[i][n] = f32x4{0.f, 0.f, 0.f, 0.f};

    auto stage = [&](int buf, int k0) {
#pragma unroll
        for (int p = 0; p < PA; ++p) {
            const int j = p * 256 + wave * 64 + lane;
            const int row = j >> 2, part = j & 3;
            load16_to_lds(A + (size_t)(m0 + row) * K + k0 + part * 8,
                          As + buf * (RA * 32) + (p * 256 + wave * 64) * 8);
        }
#pragma unroll
        for (int p = 0; p < PB; ++p) {
            const int j = p * 256 + wave * 64 + lane;
            const int row = j >> 2, part = j & 3;
            load16_to_lds(Bt + (size_t)(n0 + row) * K + k0 + part * 8,
                          Bs + buf * (RB * 32) + (p * 256 + wave * 64) * 8);
        }
    };

    const int nt = K >> 5;
    stage(0, 0);
    int cur = 0;
    for (int t = 0; t < nt; ++t) {
        __syncthreads();          // drains vmcnt: buf[cur] ready; buf[cur^1] free
        if (t + 1 < nt) stage(cur ^ 1, (t + 1) * 32);
#pragma unroll
        for (int i = 0; i < IM; ++i) {
            f16x8 a = *(const f16x8*)(As + cur * (RA * 32) + (wm + i * 16 + l16) * 32 + quad * 8);
#pragma unroll
            for (int n = 0; n < IN; ++n) {
                f16x8 b = *(const f16x8*)(Bs + cur * (RB * 32) + (wn + n * 16 + l16) * 32 + quad * 8);
                acc[i][n] = __builtin_amdgcn_mfma_f32_16x16x32_f16(a, b, acc[i][n], 0, 0, 0);
            }
        }
        cur ^= 1;
    }
#pragma unroll
    for (int i = 0; i < IM; ++i)
#pragma unroll
        for (int n = 0; n < IN; ++n)
#pragma unroll
            for (int r = 0; r < 4; ++r) {
                const int row = m0 + wm + i * 16 + quad * 4 + r;
                const int col = n0 + wn + n * 16 + l16;
                const float bv = bias_row ? bias[row] : bias[col];
                C[(size_t)row * N + col] = (OutT)(acc[i][n][r] + bv);
            }
}

// merged QK-projection + V^T-projection: 768 uniform blocks = EXACTLY 3/CU (R13)
__global__ __launch_bounds__(256, 3) void gemm_qkv(const _Float16* __restrict__ Xh,
                                                   const _Float16* __restrict__ Wqkvt,
                                                   const float* __restrict__ bqkv,
                                                   _Float16* __restrict__ QKh,
                                                   _Float16* __restrict__ VtG) {
    __shared__ __align__(16) _Float16 As[2 * 192 * 32];   // 24 KB (max of both)
    __shared__ __align__(16) _Float16 Bs[2 * 192 * 32];   // 24 KB
    const int bid = blockIdx.x;
    if (bid < 512) {       // QK: [8192][1536] = Xh . Wqkvt[0:1536]^T
        const int xcd = bid & 7, j = bid >> 3;     // j in [0,64)
        const int by = xcd + 8 * (j >> 3);         // A-panel (Xh rows), 8/XCD
        const int bx = j & 7;                      // 8 cols of 192
        gemm_body<_Float16, 4, 6>(Xh, Wqkvt, bqkv, false, QKh, 1536, DD,
                                  by * 128, bx * 192, As, Bs);
    } else {               // V^T: [768][8192] = Wv^T . Xh^T
        const int t = bid - 512;                   // t in [0,256)
        const int xcd = t & 7, j = t >> 3;         // j in [0,32)
        const int bn = xcd + 8 * (j >> 2);         // B-panel (Xh rows), 8/XCD
        const int bm = j & 3;                      // 4 rows of 192
        gemm_body<_Float16, 6, 4>(Wqkvt + (size_t)1536 * DD, Xh, bqkv + 1536, true, VtG,
                                  8192, DD, bm * 192, bn * 128, As, Bs);
    }
}

// ---------------- gemm_out: 64x128 tiles via the same template (R13) ----------------
__global__ __launch_bounds__(256) void gemm_out(const _Float16* __restrict__ A,
                                                const _Float16* __restrict__ Bt,
                                                const float* __restrict__ bias,
                                                float* __restrict__ C) {
    __shared__ __align__(16) _Float16 As[2 * 64 * 32];    // 8 KB
    __shared__ __align__(16) _Float16 Bs[2 * 128 * 32];   // 16 KB
    const int L = blockIdx.x;
    const int xcd = L & 7, j = L >> 3;                // j in [0,96)
    const int by = xcd + 8 * (j / 6);                 // 16 A-panels per XCD
    const int bx = j % 6;
    gemm_body<float, 2, 4>(A, Bt, bias, false, C, DD, DD,
                           by * 64, bx * 128, As, Bs);
}

// ---------------- flash attention: swapped-QK^T, all-x32 PV ----------------
// R14 change vs R13's frozen R11 kernel: the PV path moves from 20 x16 MFMAs
// + 16 b64 V-reads to 8 x32 + 2 x32-lac + 4 b128 V-reads per kt per wave.
// Mechanism: permute the key->MFMA-row mapping at the K read so that QK tile
// n1's output row m corresponds to key 8*(m>>2)+(m&3)+4*n1. Then
// s[mq][n1][r] holds key 8*quad+r+4*n1, and {exp2(s[*][0]), exp2(s[*][1])}
// concatenated IS the 16x16x32 A-fragment pa8[mq] (elem j = key 8*quad+j).
// The V B-fragment becomes 8 contiguous halfs (one b128 chunk, lc=wk*4+quad).
// Ks rows sigma-permuted at staging (swap bits 2<->3 of the within-32 index,
// self-inverse) so rowK&7 = l16&7 -> same conflict-free profile as before.
__global__ __launch_bounds__(256, 5) void attn_kernel(const _Float16* __restrict__ qk,
                                                      const _Float16* __restrict__ vt,
                                                      _Float16* __restrict__ ao) {
    __shared__ __align__(16) _Float16 Ks[2][64 * 64];
    __shared__ __align__(16) _Float16 Vs[2][64 * 64];

    // ---- decode: R3's exact LPT + XCD grouping (measured-good) ----
    const int L    = blockIdx.x;
    const int xcd  = L & 7;
    const int r_   = L >> 3;          // 0..191
    const int gIdx = r_ % 3;          // group on this XCD
    const int qt   = 63 - r_ / 3;     // heavy tiles dispatch first
    const int g    = gIdx * 8 + xcd;  // head-batch group 0..23
    const int b = g / NH, h = g % NH;

    const int tid = threadIdx.x;
    const int wave = tid >> 6, lane = tid & 63, quad = lane >> 4, l16 = lane & 15;
    const int wq = wave >> 1, wk = wave & 1;   // q-half, k-half

    f16x8 ones8;
#pragma unroll
    for (int j = 0; j < 8; ++j) ones8[j] = (_Float16)1.0f;

    // ---- per-lane 32-bit staging offsets (k0 added as uniform offset) ----
    // K: LDS row j holds key sig(j) = bits-2,3-swapped j (self-inverse);
    //    16B-chunk XOR swizzle by (j&7). V: identity rows, same chunk XOR.
    int vK[2], vV[2];
#pragma unroll
    for (int p = 0; p < 2; ++p) {
        const int j   = wave * 16 + p * 8 + (lane >> 3);
        const int sig = (j & ~12) | ((j & 8) >> 1) | ((j & 4) << 1);
        const int cd  = (lane & 7) ^ (j & 7);
        vK[p] = (b * TT + sig) * 1536 + DD + h * HDIM + cd * 8;
        vV[p] = (h * HDIM + j) * 8192 + b * TT + cd * 8;
    }
    auto stage = [&](int buf, int k0) {
        const int kK = k0 * 1536;   // uniform (SGPR) offsets
#pragma unroll
        for (int p = 0; p < 2; ++p) {
            load16_to_lds(qk + (vK[p] + kK), Ks[buf] + (wave * 16 + p * 8) * 64);
            load16_to_lds(vt + (vV[p] + k0), Vs[buf] + (wave * 16 + p * 8) * 64);
        }
    };

    const int q0 = qt * 64;
    const int nkt = qt + 1;
    const int qrow0 = q0 + wq * 32;                 // wave's first q-row
    const int qr_lane = qrow0 + l16;                // lane's q (S^T col); +16 for mq=1
    // QK A-row m=l16 of tile n1 <-> key 8*(l16>>2)+(l16&3)+4*n1; its LDS row
    // rho(key) = 16*(l16>>3) + 8*n1 + 4*((l16>>2)&1) + (l16&3)  (rho&7 = l16&7)
    const int rowKbase = wk * 32 + 16 * (l16 >> 3) + 4 * ((l16 >> 2) & 1) + (l16 & 3);
    // Q fragments (B-operand of the swapped QK), pre-scaled by SC2
    f16x8 aq[2][2];
#pragma unroll
    for (int mq = 0; mq < 2; ++mq) {
        const int qoff = (b * TT + qrow0 + mq * 16 + l16) * 1536 + h * HDIM + quad * 8;
        const _Float16 sc = (_Float16)SC2;
        aq[mq][0] = *(const f16x8*)(qk + qoff) * sc;
        aq[mq][1] = *(const f16x8*)(qk + qoff + 32) * sc;
    }
    f32x4 o[2][4], lac[2];
#pragma unroll
    for (int mq = 0; mq < 2; ++mq) {
#pragma unroll
        for (int n = 0; n < 4; ++n) o[mq][n] = f32x4{0.f, 0.f, 0.f, 0.f};
        lac[mq] = f32x4{0.f, 0.f, 0.f, 0.f};
    }

    stage(0, 0);              // prime the pipeline
    int cur = 0;
    for (int kt = 0; kt < nkt; ++kt) {
        __syncthreads();      // drains vmcnt: tile kt published; other buf free
        if (kt + 1 < nkt) stage(cur ^ 1, (kt + 1) * 64);

        f32x4 s[2][2];
        f16x8 pa8[2];         // x32 A-frags: elem j = P[q][key 8*quad+j]
#pragma unroll
        for (int mq = 0; mq < 2; ++mq)
#pragma unroll
            for (int n1 = 0; n1 < 2; ++n1) s[mq][n1] = f32x4{0.f, 0.f, 0.f, 0.f};

        auto qk_half = [&](int n1) {
#pragma unroll
            for (int kh = 0; kh < 2; ++kh) {
                const int rowK = rowKbase + 8 * n1;                 // permuted key row
                const int pos = (kh * 4 + quad) ^ (l16 & 7);        // d-chunk swizzle
                f16x8 bk = *(const f16x8*)(Ks[cur] + rowK * 64 + pos * 8);
                s[0][n1] = __builtin_amdgcn_mfma_f32_16x16x32_f16(bk, aq[0][kh], s[0][n1], 0, 0, 0);
                s[1][n1] = __builtin_amdgcn_mfma_f32_16x16x32_f16(bk, aq[1][kh], s[1][n1], 0, 0, 0);
            }
        };
        auto mask_half = [&](int n1) {
#pragma unroll
            for (int mq = 0; mq < 2; ++mq) {
                const int qr = qr_lane + mq * 16;
                const int kg0 = kt * 64 + wk * 32 + 8 * quad + 4 * n1;   // permuted key
#pragma unroll
                for (int r = 0; r < 4; ++r)
                    if (kg0 + r > qr) s[mq][n1][r] = -1e30f;
            }
        };
        auto exp_half = [&](int n1) {
#pragma unroll
            for (int mq = 0; mq < 2; ++mq)
#pragma unroll
                for (int r = 0; r < 4; ++r)
                    pa8[mq][n1 * 4 + r] = (_Float16)__builtin_amdgcn_exp2f(s[mq][n1][r]);
        };

        const bool last = (kt == nkt - 1);
        __builtin_amdgcn_s_setprio(1);
        qk_half(0);
        __builtin_amdgcn_s_setprio(0);
        if (last) mask_half(0);
        exp_half(0);
        __builtin_amdgcn_s_setprio(1);
        qk_half(1);           // MFMA overlaps exp(0)'s trans ops
        __builtin_amdgcn_s_setprio(0);
        if (last) mask_half(1);
        exp_half(1);

        // ---- PV + l, all x32 (keys = wave's 32, one MFMA per (mq,n)) ----
        __builtin_amdgcn_s_setprio(1);
        lac[0] = __builtin_amdgcn_mfma_f32_16x16x32_f16(pa8[0], ones8, lac[0], 0, 0, 0);
        lac[1] = __builtin_amdgcn_mfma_f32_16x16x32_f16(pa8[1], ones8, lac[1], 0, 0, 0);
#pragma unroll
        for (int n = 0; n < 4; ++n) {
            const int rowV = n * 16 + l16;                       // d row
            const int pc = (wk * 4 + quad) ^ (l16 & 7);          // phys 16B chunk
            f16x8 bv = *(const f16x8*)(Vs[cur] + rowV * 64 + pc * 8);
            o[0][n] = __builtin_amdgcn_mfma_f32_16x16x32_f16(pa8[0], bv, o[0][n], 0, 0, 0);
            o[1][n] = __builtin_amdgcn_mfma_f32_16x16x32_f16(pa8[1], bv, o[1][n], 0, 0, 0);
        }
        __builtin_amdgcn_s_setprio(0);
        cur ^= 1;
    }

    // ---- k-half combine via LDS (block-local, no fences) ----
    __syncthreads();          // all LDS reads of the loop complete
    float* const Ksf = (float*)&Ks[0][0];   // o scratch: 8 KB per wq
    float* const Vsf = (float*)&Vs[0][0];   // lac scratch (first 256 B)
    if (wk) {
#pragma unroll
        for (int mq = 0; mq < 2; ++mq) {
            if (l16 == 0)
                *(f32x4*)(Vsf + wq * 32 + mq * 16 + quad * 4) = lac[mq];
#pragma unroll
            for (int n = 0; n < 4; ++n)
                *(f32x4*)(Ksf + wq * 2048 + (mq * 4 + n) * 256 + lane * 4) = o[mq][n];
        }
    }
    __syncthreads();          // partials visible block-wide
    if (!wk) {
#pragma unroll
        for (int mq = 0; mq < 2; ++mq) {
            f32x4 lp = *(const f32x4*)(Vsf + wq * 32 + mq * 16 + quad * 4);
            f32x4 inv;
#pragma unroll
            for (int r = 0; r < 4; ++r) inv[r] = 1.0f / (lac[mq][r] + lp[r]);
#pragma unroll
            for (int n = 0; n < 4; ++n) {
                f32x4 op = *(const f32x4*)(Ksf + wq * 2048 + (mq * 4 + n) * 256 + lane * 4);
#pragma unroll
                for (int r = 0; r < 4; ++r) {
                    const int ooff = (b * TT + qrow0 + mq * 16 + quad * 4 + r) * DD + h * HDIM + l16;
                    ao[ooff + n * 16] = (_Float16)((o[mq][n][r] + op[r]) * inv[r]);
                }
            }
        }
    }
}

// ---------------- launch ----------------
extern "C" void kernel_launch(void* const* d_in, const int* in_sizes, int n_in,
                              void* d_out, int out_size, void* d_ws, size_t ws_size,
                              hipStream_t stream) {
    const float* x     = (const float*)d_in[0];   // [2,4096,768]
    const float* Wqkv  = (const float*)d_in[1];   // [768,2304]
    const float* bqkv  = (const float*)d_in[2];   // [2304]
    const float* Wout  = (const float*)d_in[3];   // [768,768]
    const float* bout  = (const float*)d_in[4];   // [768]
    float* out = (float*)d_out;                   // [2,4096,768]

    char* ws = (char*)d_ws;
    _Float16* Xh    = (_Float16*)ws;  ws += (size_t)BB * TT * DD * 2;    // 12.6 MB
    _Float16* Wqkvt = (_Float16*)ws;  ws += (size_t)D3 * DD * 2;         // 3.5 MB
    _Float16* Wot   = (_Float16*)ws;  ws += (size_t)DD * DD * 2;         // 1.2 MB
    _Float16* QKh   = (_Float16*)ws;  ws += (size_t)BB * TT * 1536 * 2;  // 25.2 MB
    _Float16* VtG   = (_Float16*)ws;  ws += (size_t)DD * BB * TT * 2;    // 12.6 MB
    _Float16* AOh   = (_Float16*)ws;  ws += (size_t)BB * TT * DD * 2;    // 12.6 MB

    prep<<<8448, 256, 0, stream>>>(x, Xh, Wqkv, Wqkvt, Wout, Wot);

    gemm_qkv<<<768, 256, 0, stream>>>(Xh, Wqkvt, bqkv, QKh, VtG);

    attn_kernel<<<1536, 256, 0, stream>>>(QKh, VtG, AOh);

    gemm_out<<<768, 256, 0, stream>>>(AOh, Wot, bout, out);
}